// Round 13
// baseline (601.537 us; speedup 1.0000x reference)
//
#include <hip/hip_runtime.h>
#include <hip/hip_bf16.h>
#include <cstdint>
#include <cstddef>

// Problem dims
#define HD   768
#define ID   3072
#define NB   4
#define SL   2048
#define NL   4
#define ROWS (NB*SL)   // 8192

typedef __attribute__((ext_vector_type(8))) short bf16x8s;
typedef __attribute__((ext_vector_type(4))) float f32x4;
typedef __attribute__((ext_vector_type(4))) unsigned short u16x4;

typedef __attribute__((address_space(1))) const unsigned int g_as1_u32;
typedef __attribute__((address_space(3))) unsigned int lds_as3_u32;

// async 16B/lane global->LDS copy (wave-uniform LDS base + lane*16)
__device__ __forceinline__ void gl2lds16(__hip_bfloat16* l, const __hip_bfloat16* g) {
  __builtin_amdgcn_global_load_lds((g_as1_u32*)g, (lds_as3_u32*)l, 16, 0, 0);
}

__device__ __forceinline__ float bfu2f(unsigned short u) {
  return __uint_as_float((unsigned int)u << 16);
}
__device__ __forceinline__ unsigned short f2bfu(float f) {
  __hip_bfloat16 h = __float2bfloat16(f);
  return *reinterpret_cast<unsigned short*>(&h);
}

// ---------------------------------------------------------------------------
// Wave-per-row LayerNorm: block=256 (4 waves), wave w does row blockIdx*4+w.
// ---------------------------------------------------------------------------
template <int OUTF32>
__global__ __launch_bounds__(256) void ln_row_kernel(
    const __hip_bfloat16* __restrict__ x,
    const float* __restrict__ scale, const float* __restrict__ bias,
    __hip_bfloat16* __restrict__ ob, float* __restrict__ of)
{
  const int w = threadIdx.x >> 6, lane = threadIdx.x & 63;
  const size_t row = (size_t)blockIdx.x * 4 + w;
  const __hip_bfloat16* xr = x + row * HD;
  float v[12];
#pragma unroll
  for (int c = 0; c < 3; c++) {
    u16x4 u = *reinterpret_cast<const u16x4*>(xr + c * 256 + lane * 4);
#pragma unroll
    for (int i = 0; i < 4; i++) v[c * 4 + i] = bfu2f(u[i]);
  }
  float s = 0.f;
#pragma unroll
  for (int i = 0; i < 12; i++) s += v[i];
#pragma unroll
  for (int m = 1; m < 64; m <<= 1) s += __shfl_xor(s, m);
  float mean = s * (1.0f / 768.0f);
  float q = 0.f;
#pragma unroll
  for (int i = 0; i < 12; i++) { float d = v[i] - mean; q += d * d; }
#pragma unroll
  for (int m = 1; m < 64; m <<= 1) q += __shfl_xor(q, m);
  float rstd = rsqrtf(q * (1.0f / 768.0f) + 1e-5f);
#pragma unroll
  for (int c = 0; c < 3; c++) {
    int j0 = c * 256 + lane * 4;
    if (OUTF32) {
      f32x4 o;
#pragma unroll
      for (int i = 0; i < 4; i++)
        o[i] = (v[c * 4 + i] - mean) * rstd * scale[j0 + i] + bias[j0 + i];
      *reinterpret_cast<f32x4*>(of + row * HD + j0) = o;
    } else {
      u16x4 o;
#pragma unroll
      for (int i = 0; i < 4; i++)
        o[i] = f2bfu((v[c * 4 + i] - mean) * rstd * scale[j0 + i] + bias[j0 + i]);
      *reinterpret_cast<u16x4*>(ob + row * HD + j0) = o;
    }
  }
}

// embedding gather + pos add + LN (wave-per-row), writes bf16
__global__ __launch_bounds__(256) void embed_ln_kernel(
    const int* __restrict__ ids, const float* __restrict__ wemb,
    const float* __restrict__ pemb,
    const float* __restrict__ scale, const float* __restrict__ bias,
    __hip_bfloat16* __restrict__ ob)
{
  const int w = threadIdx.x >> 6, lane = threadIdx.x & 63;
  const size_t row = (size_t)blockIdx.x * 4 + w;
  const int t = (int)(row & (SL - 1));
  const int id = ids[row];
  float v[12];
#pragma unroll
  for (int c = 0; c < 3; c++) {
    int j0 = c * 256 + lane * 4;
    f32x4 a = *reinterpret_cast<const f32x4*>(wemb + (size_t)id * HD + j0);
    f32x4 p = *reinterpret_cast<const f32x4*>(pemb + (size_t)t * HD + j0);
#pragma unroll
    for (int i = 0; i < 4; i++) v[c * 4 + i] = a[i] + p[i];
  }
  float s = 0.f;
#pragma unroll
  for (int i = 0; i < 12; i++) s += v[i];
#pragma unroll
  for (int m = 1; m < 64; m <<= 1) s += __shfl_xor(s, m);
  float mean = s * (1.0f / 768.0f);
  float q = 0.f;
#pragma unroll
  for (int i = 0; i < 12; i++) { float d = v[i] - mean; q += d * d; }
#pragma unroll
  for (int m = 1; m < 64; m <<= 1) q += __shfl_xor(q, m);
  float rstd = rsqrtf(q * (1.0f / 768.0f) + 1e-5f);
#pragma unroll
  for (int c = 0; c < 3; c++) {
    int j0 = c * 256 + lane * 4;
    u16x4 o;
#pragma unroll
    for (int i = 0; i < 4; i++)
      o[i] = f2bfu((v[c * 4 + i] - mean) * rstd * scale[j0 + i] + bias[j0 + i]);
    *reinterpret_cast<u16x4*>(ob + row * HD + j0) = o;
  }
}

// ---------------------------------------------------------------------------
// Weight transpose + f32->bf16: in [K][N] f32 -> out [N][K] bf16, grid.z = layer
// ---------------------------------------------------------------------------
__global__ __launch_bounds__(256) void transpose_bf16_kernel(
    const float* __restrict__ in, __hip_bfloat16* __restrict__ out, int K, int N)
{
  __shared__ float tile[32][33];
  const float* inp = in + (size_t)blockIdx.z * K * N;
  __hip_bfloat16* outp = out + (size_t)blockIdx.z * K * N;
  int n0 = blockIdx.x * 32, k0 = blockIdx.y * 32;
  int tx = threadIdx.x, ty = threadIdx.y;   // (32, 8)
#pragma unroll
  for (int i = 0; i < 4; i++)
    tile[ty + i * 8][tx] = inp[(size_t)(k0 + ty + i * 8) * N + n0 + tx];
  __syncthreads();
#pragma unroll
  for (int i = 0; i < 4; i++)
    outp[(size_t)(n0 + ty + i * 8) * K + k0 + tx] = __float2bfloat16(tile[tx][ty + i * 8]);
}

// ---------------------------------------------------------------------------
// Retention scan + residual fuse: r_t = 0.5*s_t + 0.5*r_{t-1};
// writes z = h + r (bf16). 64-chunk with 64-step warm-up (0.5^64 -> exact).
// ---------------------------------------------------------------------------
__global__ __launch_bounds__(256) void scan_kernel(
    const __hip_bfloat16* __restrict__ s,
    const __hip_bfloat16* __restrict__ h,
    __hip_bfloat16* __restrict__ z)
{
  int bid = blockIdx.x;             // b*96 + chunk*3 + sub
  int sub = bid % 3;
  int chunk = (bid / 3) % 32;
  int b = bid / 96;
  int hh = sub * 256 + threadIdx.x;
  int tstart = chunk * 64;
  int t0 = tstart - 64; if (t0 < 0) t0 = 0;
  const __hip_bfloat16* sp = s + (size_t)b * SL * HD + hh;
  const __hip_bfloat16* hp = h + (size_t)b * SL * HD + hh;
  __hip_bfloat16* zp = z + (size_t)b * SL * HD + hh;
  float acc = 0.f;
#pragma unroll 8
  for (int t = t0; t < tstart; ++t)
    acc = 0.5f * (__bfloat162float(sp[(size_t)t * HD]) + acc);
#pragma unroll 8
  for (int t = tstart; t < tstart + 64; ++t) {
    acc = 0.5f * (__bfloat162float(sp[(size_t)t * HD]) + acc);
    zp[(size_t)t * HD] = __float2bfloat16(acc + __bfloat162float(hp[(size_t)t * HD]));
  }
}

// ---------------------------------------------------------------------------
// Counted-vmcnt pipelined MFMA GEMM, 2 blocks/CU (r12 base) + sub-phase
// overlap + T5 setprio.
// Per K-step: vmcnt(L) -> s_barrier -> ds_read all frags -> MFMA(kk0)
//   [kk1 reads complete under kk0 MFMAs] -> lgkm(0) -> s_barrier ->
//   stage(t+2) -> MFMA(kk1) [stage issue hidden].
// Invariant: all this wave's ds_reads precede the lgkm(0) ("memory" asm
// pins C++ loads); barrier2 then guarantees no wave still reads the buffer
// stage(t+2) overwrites. MFMAs are register-only and schedule freely.
// T2 slot-XOR swizzle as r12. LDS dbuf 64/56 KB -> 2 blocks/CU.
// C[M,N] = act(A[M,K] @ Bt[N,K]^T + bias) [+ R], bf16 out.
// ---------------------------------------------------------------------------
template <int BN, int ACT, int RADD>
__global__ __launch_bounds__(256, 2) void gemm_mfma_kernel(
    const __hip_bfloat16* __restrict__ A,
    const __hip_bfloat16* __restrict__ Bt,
    const float* __restrict__ bias,
    const __hip_bfloat16* __restrict__ R,
    __hip_bfloat16* __restrict__ Cb,
    int M, int N, int K)
{
  constexpr int NF = BN / 32;               // N-frags per wave: 4 or 3
  constexpr int ABUF = 128 * 64;            // A buffer elems (16KB)
  constexpr int BBUF = BN * 64;             // B buffer elems (16/12KB)
  __shared__ __align__(16) __hip_bfloat16 As[2 * ABUF];
  __shared__ __align__(16) __hip_bfloat16 Bs[2 * BBUF];
  const int m0 = blockIdx.x * 128;
  const int n0 = blockIdx.y * BN;
  const int tid  = threadIdx.x;
  const int lane = tid & 63;
  const int w    = tid >> 6;                // wave 0..3
  const int wr   = w >> 1;                  // 0..1 (M half, 64 rows)
  const int wc   = w & 1;                   // 0..1 (N half)
  const int lr   = lane & 15;
  const int kg   = lane >> 4;               // 0..3

  f32x4 acc[4][NF];
#pragma unroll
  for (int i = 0; i < 4; i++)
#pragma unroll
    for (int j = 0; j < NF; j++) acc[i][j] = (f32x4){0.f, 0.f, 0.f, 0.f};

  // staging: pass = 256 thr x 16B = 32 rows x 128B. Wave w rows w*8..w*8+7.
  // lane l: row w*8 + l/8, LDS slot l%8, global k-slot (l%8)^(l/8).
  const int prow = lane >> 3;               // 0..7
  const int pslot = lane & 7;
  const int gslot = pslot ^ prow;
  const __hip_bfloat16* aS = A  + (size_t)(m0 + w * 8 + prow) * K + gslot * 8;
  const __hip_bfloat16* bS = Bt + (size_t)(n0 + w * 8 + prow) * K + gslot * 8;
  const size_t K32g = (size_t)32 * K;       // 32-row pass stride (global)
  const int ldsw = w << 9;                  // w*512 elems (8 rows x 64)

  // per-wave loads per stage: A 4 passes + B NF passes = 8 (BN=128) / 7 (96)
  auto stage = [&](int buf, int k0) {
    __hip_bfloat16* Ab = As + buf * ABUF + ldsw;
    __hip_bfloat16* Bb = Bs + buf * BBUF + ldsw;
    gl2lds16(Ab,         aS + k0);               // A rows 0-31
    gl2lds16(Ab + 2048,  aS + k0 + K32g);        // A rows 32-63
    gl2lds16(Ab + 4096,  aS + k0 + 2 * K32g);    // A rows 64-95
    gl2lds16(Ab + 6144,  aS + k0 + 3 * K32g);    // A rows 96-127
    gl2lds16(Bb,         bS + k0);               // B rows 0-31
    gl2lds16(Bb + 2048,  bS + k0 + K32g);        // B rows 32-63
    gl2lds16(Bb + 4096,  bS + k0 + 2 * K32g);    // B rows 64-95
    if constexpr (BN == 128)
      gl2lds16(Bb + 6144, bS + k0 + 3 * K32g);   // B rows 96-127
  };

  // read-side swizzled slots (per-lane constants)
  const int rx = lr & 7;
  const int arow = wr * 64 + lr;            // + i*16
  const int brow = wc * (BN / 2) + lr;      // + j*16

  const int nt = K >> 6;                    // BK=64 tiles (12 or 48)
  stage(0, 0);
  stage(1, 64);

  for (int t = 0; t < nt; ++t) {
    const int cur = t & 1;
    // counted wait: tile t's own loads done; tile t+1's stay in flight
    if (t == nt - 1) {
      asm volatile("s_waitcnt vmcnt(0)" ::: "memory");
    } else {
      if constexpr (BN == 128) asm volatile("s_waitcnt vmcnt(8)" ::: "memory");
      else                     asm volatile("s_waitcnt vmcnt(7)" ::: "memory");
    }
    asm volatile("s_barrier" ::: "memory");          // all waves: tile t ready

    const __hip_bfloat16* Ab = As + cur * ABUF;
    const __hip_bfloat16* Bb = Bs + cur * BBUF;
    bf16x8s af[2][4], bq[2][NF];
#pragma unroll
    for (int kk = 0; kk < 2; kk++) {
      const int sl = ((kk * 4 + kg) ^ rx) * 8;
#pragma unroll
      for (int i = 0; i < 4; i++)
        af[kk][i] = *reinterpret_cast<const bf16x8s*>(&Ab[(arow + i * 16) * 64 + sl]);
#pragma unroll
      for (int j = 0; j < NF; j++)
        bq[kk][j] = *reinterpret_cast<const bf16x8s*>(&Bb[(brow + j * 16) * 64 + sl]);
    }

    // MFMA kk0 — kk1's ds_reads complete underneath (compiler auto-lgkm)
    __builtin_amdgcn_s_setprio(1);
#pragma unroll
    for (int i = 0; i < 4; i++)
#pragma unroll
      for (int j = 0; j < NF; j++)
        acc[i][j] = __builtin_amdgcn_mfma_f32_16x16x32_bf16(
            af[0][i], bq[0][j], acc[i][j], 0, 0, 0);
    __builtin_amdgcn_s_setprio(0);

    asm volatile("s_waitcnt lgkmcnt(0)" ::: "memory");  // this wave's reads done
    asm volatile("s_barrier" ::: "memory");             // all waves done reading

    if (t + 2 < nt) stage(cur, (t + 2) << 6);  // overwrite just-read buffer

    // MFMA kk1 — stage issue hidden underneath
    __builtin_amdgcn_s_setprio(1);
#pragma unroll
    for (int i = 0; i < 4; i++)
#pragma unroll
      for (int j = 0; j < NF; j++)
        acc[i][j] = __builtin_amdgcn_mfma_f32_16x16x32_bf16(
            af[1][i], bq[1][j], acc[i][j], 0, 0, 0);
    __builtin_amdgcn_s_setprio(0);
  }

#pragma unroll
  for (int i = 0; i < 4; i++)
#pragma unroll
    for (int j = 0; j < NF; j++) {
      int col = n0 + wc * (BN / 2) + j * 16 + lr;
      float bv = bias[col];
#pragma unroll
      for (int r = 0; r < 4; r++) {
        int row = m0 + wr * 64 + i * 16 + kg * 4 + r;
        float v = acc[i][j][r] + bv;
        if (ACT == 1) v = 1.f / (1.f + __expf(-v));
        else if (ACT == 2) {
          float x = v;
          float z = 1.5957691216057308f * (x + 0.044715f * x * x * x);
          v = x / (1.f + __expf(-z));
        }
        if (RADD) v += __bfloat162float(R[(size_t)row * N + col]);
        Cb[(size_t)row * N + col] = __float2bfloat16(v);
      }
    }
}

// ---------------------------------------------------------------------------
extern "C" void kernel_launch(void* const* d_in, const int* in_sizes, int n_in,
                              void* d_out, int out_size, void* d_ws, size_t ws_size,
                              hipStream_t stream)
{
  const int*   ids  = (const int*)d_in[0];
  const float* wemb = (const float*)d_in[1];
  const float* pemb = (const float*)d_in[2];
  const float* elns = (const float*)d_in[3];
  const float* elnb = (const float*)d_in[4];
  const float* retW = (const float*)d_in[5];
  const float* retb = (const float*)d_in[6];
  const float* ln1s = (const float*)d_in[7];
  const float* ln1b = (const float*)d_in[8];
  const float* W1   = (const float*)d_in[9];
  const float* b1   = (const float*)d_in[10];
  const float* W2   = (const float*)d_in[11];
  const float* b2   = (const float*)d_in[12];
  const float* ln2s = (const float*)d_in[13];
  const float* ln2b = (const float*)d_in[14];
  const float* fins = (const float*)d_in[15];
  const float* finb = (const float*)d_in[16];
  float* out = (float*)d_out;

  char* ws = (char*)d_ws;
  size_t off = 0;
  __hip_bfloat16* retWt = (__hip_bfloat16*)(ws + off); off += (size_t)NL * HD * HD * 2;
  __hip_bfloat16* W1t   = (__hip_bfloat16*)(ws + off); off += (size_t)NL * HD * ID * 2;
  __hip_bfloat16* W2t   = (__hip_bfloat16*)(ws + off); off += (size_t)NL * ID * HD * 2;
  __hip_bfloat16* hb    = (__hip_bfloat16*)(ws + off); off += (size_t)ROWS * HD * 2;  // residual h
  __hip_bfloat16* h1b   = (__hip_bfloat16*)(ws + off); off += (size_t)ROWS * HD * 2;  // h1
  __hip_bfloat16* zb    = (__hip_bfloat16*)(ws + off); off += (size_t)ROWS * HD * 2;  // h+r / h1+ffn2
  __hip_bfloat16* gb    = (__hip_bfloat16*)(ws + off); off += (size_t)ROWS * ID * 2;  // s / gelu out
  __hip_bfloat16* sb = gb;
  __hip_bfloat16* yb = zb;

  dim3 tb(32, 8);
  transpose_bf16_kernel<<<dim3(HD/32, HD/32, NL), tb, 0, stream>>>(retW, retWt, HD, HD);
  transpose_bf16_kernel<<<dim3(ID/32, HD/32, NL), tb, 0, stream>>>(W1, W1t, HD, ID);
  transpose_bf16_kernel<<<dim3(HD/32, ID/32, NL), tb, 0, stream>>>(W2, W2t, ID, HD);

  embed_ln_kernel<<<ROWS/4, 256, 0, stream>>>(ids, wemb, pemb, elns, elnb, hb);

  for (int l = 0; l < NL; l++) {
    // s = sigmoid(h @ retW + rb) -> sb (bf16). BN=96 (512 blocks = 2/CU)
    gemm_mfma_kernel<96, 1, 0><<<dim3(ROWS/128, HD/96), 256, 0, stream>>>(
        hb, retWt + (size_t)l * HD * HD, retb + (size_t)l * HD,
        nullptr, sb, ROWS, HD, HD);
    // z = h + retention(s) -> zb (bf16)
    scan_kernel<<<NB * 32 * 3, 256, 0, stream>>>(sb, hb, zb);
    // h1 = LN(z)
    ln_row_kernel<0><<<ROWS/4, 256, 0, stream>>>(zb,
        ln1s + (size_t)l * HD, ln1b + (size_t)l * HD, h1b, nullptr);
    // g = gelu(h1 @ W1 + b1) -> gb (bf16). BN=128 (1536 blocks)
    gemm_mfma_kernel<128, 2, 0><<<dim3(ROWS/128, ID/128), 256, 0, stream>>>(
        h1b, W1t + (size_t)l * ID * HD, b1 + (size_t)l * ID,
        nullptr, gb, ROWS, ID, HD);
    // y = h1 + (g @ W2 + b2) -> yb (bf16). BN=96 (512 blocks = 2/CU)
    gemm_mfma_kernel<96, 0, 1><<<dim3(ROWS/128, HD/96), 256, 0, stream>>>(
        gb, W2t + (size_t)l * HD * ID, b2 + (size_t)l * HD,
        h1b, yb, ROWS, HD, ID);
    // h = LN(y)
    ln_row_kernel<0><<<ROWS/4, 256, 0, stream>>>(yb,
        ln2s + (size_t)l * HD, ln2b + (size_t)l * HD, hb, nullptr);
  }
  // final LN -> d_out (f32)
  ln_row_kernel<1><<<ROWS/4, 256, 0, stream>>>(hb, fins, finb, nullptr, out);
}

// Round 17
// 565.131 us; speedup vs baseline: 1.0644x; 1.0644x over previous
//
#include <hip/hip_runtime.h>
#include <hip/hip_bf16.h>
#include <cstdint>
#include <cstddef>

// Problem dims
#define HD   768
#define ID   3072
#define NB   4
#define SL   2048
#define NL   4
#define ROWS (NB*SL)   // 8192

typedef __attribute__((ext_vector_type(8))) short bf16x8s;
typedef __attribute__((ext_vector_type(4))) float f32x4;
typedef __attribute__((ext_vector_type(4))) unsigned short u16x4;

typedef __attribute__((address_space(1))) const unsigned int g_as1_u32;
typedef __attribute__((address_space(3))) unsigned int lds_as3_u32;

// async 16B/lane global->LDS copy (wave-uniform LDS base + lane*16)
__device__ __forceinline__ void gl2lds16(__hip_bfloat16* l, const __hip_bfloat16* g) {
  __builtin_amdgcn_global_load_lds((g_as1_u32*)g, (lds_as3_u32*)l, 16, 0, 0);
}

__device__ __forceinline__ float bfu2f(unsigned short u) {
  return __uint_as_float((unsigned int)u << 16);
}
__device__ __forceinline__ unsigned short f2bfu(float f) {
  __hip_bfloat16 h = __float2bfloat16(f);
  return *reinterpret_cast<unsigned short*>(&h);
}

// ---------------------------------------------------------------------------
// Wave-per-row LayerNorm: block=256 (4 waves), wave w does row blockIdx*4+w.
// ---------------------------------------------------------------------------
template <int OUTF32>
__global__ __launch_bounds__(256) void ln_row_kernel(
    const __hip_bfloat16* __restrict__ x,
    const float* __restrict__ scale, const float* __restrict__ bias,
    __hip_bfloat16* __restrict__ ob, float* __restrict__ of)
{
  const int w = threadIdx.x >> 6, lane = threadIdx.x & 63;
  const size_t row = (size_t)blockIdx.x * 4 + w;
  const __hip_bfloat16* xr = x + row * HD;
  float v[12];
#pragma unroll
  for (int c = 0; c < 3; c++) {
    u16x4 u = *reinterpret_cast<const u16x4*>(xr + c * 256 + lane * 4);
#pragma unroll
    for (int i = 0; i < 4; i++) v[c * 4 + i] = bfu2f(u[i]);
  }
  float s = 0.f;
#pragma unroll
  for (int i = 0; i < 12; i++) s += v[i];
#pragma unroll
  for (int m = 1; m < 64; m <<= 1) s += __shfl_xor(s, m);
  float mean = s * (1.0f / 768.0f);
  float q = 0.f;
#pragma unroll
  for (int i = 0; i < 12; i++) { float d = v[i] - mean; q += d * d; }
#pragma unroll
  for (int m = 1; m < 64; m <<= 1) q += __shfl_xor(q, m);
  float rstd = rsqrtf(q * (1.0f / 768.0f) + 1e-5f);
#pragma unroll
  for (int c = 0; c < 3; c++) {
    int j0 = c * 256 + lane * 4;
    if (OUTF32) {
      f32x4 o;
#pragma unroll
      for (int i = 0; i < 4; i++)
        o[i] = (v[c * 4 + i] - mean) * rstd * scale[j0 + i] + bias[j0 + i];
      *reinterpret_cast<f32x4*>(of + row * HD + j0) = o;
    } else {
      u16x4 o;
#pragma unroll
      for (int i = 0; i < 4; i++)
        o[i] = f2bfu((v[c * 4 + i] - mean) * rstd * scale[j0 + i] + bias[j0 + i]);
      *reinterpret_cast<u16x4*>(ob + row * HD + j0) = o;
    }
  }
}

// embedding gather + pos add + LN (wave-per-row), writes bf16
__global__ __launch_bounds__(256) void embed_ln_kernel(
    const int* __restrict__ ids, const float* __restrict__ wemb,
    const float* __restrict__ pemb,
    const float* __restrict__ scale, const float* __restrict__ bias,
    __hip_bfloat16* __restrict__ ob)
{
  const int w = threadIdx.x >> 6, lane = threadIdx.x & 63;
  const size_t row = (size_t)blockIdx.x * 4 + w;
  const int t = (int)(row & (SL - 1));
  const int id = ids[row];
  float v[12];
#pragma unroll
  for (int c = 0; c < 3; c++) {
    int j0 = c * 256 + lane * 4;
    f32x4 a = *reinterpret_cast<const f32x4*>(wemb + (size_t)id * HD + j0);
    f32x4 p = *reinterpret_cast<const f32x4*>(pemb + (size_t)t * HD + j0);
#pragma unroll
    for (int i = 0; i < 4; i++) v[c * 4 + i] = a[i] + p[i];
  }
  float s = 0.f;
#pragma unroll
  for (int i = 0; i < 12; i++) s += v[i];
#pragma unroll
  for (int m = 1; m < 64; m <<= 1) s += __shfl_xor(s, m);
  float mean = s * (1.0f / 768.0f);
  float q = 0.f;
#pragma unroll
  for (int i = 0; i < 12; i++) { float d = v[i] - mean; q += d * d; }
#pragma unroll
  for (int m = 1; m < 64; m <<= 1) q += __shfl_xor(q, m);
  float rstd = rsqrtf(q * (1.0f / 768.0f) + 1e-5f);
#pragma unroll
  for (int c = 0; c < 3; c++) {
    int j0 = c * 256 + lane * 4;
    u16x4 o;
#pragma unroll
    for (int i = 0; i < 4; i++)
      o[i] = f2bfu((v[c * 4 + i] - mean) * rstd * scale[j0 + i] + bias[j0 + i]);
    *reinterpret_cast<u16x4*>(ob + row * HD + j0) = o;
  }
}

// ---------------------------------------------------------------------------
// Weight transpose + f32->bf16: in [K][N] f32 -> out [N][K] bf16, grid.z = layer
// ---------------------------------------------------------------------------
__global__ __launch_bounds__(256) void transpose_bf16_kernel(
    const float* __restrict__ in, __hip_bfloat16* __restrict__ out, int K, int N)
{
  __shared__ float tile[32][33];
  const float* inp = in + (size_t)blockIdx.z * K * N;
  __hip_bfloat16* outp = out + (size_t)blockIdx.z * K * N;
  int n0 = blockIdx.x * 32, k0 = blockIdx.y * 32;
  int tx = threadIdx.x, ty = threadIdx.y;   // (32, 8)
#pragma unroll
  for (int i = 0; i < 4; i++)
    tile[ty + i * 8][tx] = inp[(size_t)(k0 + ty + i * 8) * N + n0 + tx];
  __syncthreads();
#pragma unroll
  for (int i = 0; i < 4; i++)
    outp[(size_t)(n0 + ty + i * 8) * K + k0 + tx] = __float2bfloat16(tile[tx][ty + i * 8]);
}

// ---------------------------------------------------------------------------
// Fused retention scan + residual + LN1.
// Block (b, chunk of 32 timesteps), 768 threads (12 waves), 1 column/thread.
// Phase 1: 64-step warm-up (0.5^64 -> exact) + 32 steps z = h + r -> LDS.
// Phase 2: wave-per-row LN over the 32x768 LDS tile -> h1 (bf16).
// Saves the z HBM round-trip (25 MB/layer) and one launch per layer.
// ---------------------------------------------------------------------------
__global__ __launch_bounds__(768) void scan_ln_kernel(
    const __hip_bfloat16* __restrict__ s,
    const __hip_bfloat16* __restrict__ h,
    const float* __restrict__ scale, const float* __restrict__ bias,
    __hip_bfloat16* __restrict__ h1)
{
  __shared__ __hip_bfloat16 zt[32][HD];     // 48 KB
  const int col = threadIdx.x;              // 0..767
  const int nchunk = SL / 32;               // 64
  const int c = blockIdx.x & (nchunk - 1);
  const int b = blockIdx.x / nchunk;
  const int tstart = c * 32;
  int t0 = tstart - 64; if (t0 < 0) t0 = 0;
  const __hip_bfloat16* sp = s + (size_t)b * SL * HD + col;
  const __hip_bfloat16* hp = h + (size_t)b * SL * HD + col;
  float acc = 0.f;
#pragma unroll 8
  for (int t = t0; t < tstart; ++t)
    acc = 0.5f * (__bfloat162float(sp[(size_t)t * HD]) + acc);
#pragma unroll 8
  for (int tt = 0; tt < 32; ++tt) {
    int t = tstart + tt;
    acc = 0.5f * (__bfloat162float(sp[(size_t)t * HD]) + acc);
    zt[tt][col] = __float2bfloat16(acc + __bfloat162float(hp[(size_t)t * HD]));
  }
  __syncthreads();
  // LN phase: 12 waves, wave wv handles rows wv, wv+12, wv+24 (<32)
  const int wv = threadIdx.x >> 6, lane = threadIdx.x & 63;
  for (int row = wv; row < 32; row += 12) {
    float v[12];
#pragma unroll
    for (int cc = 0; cc < 3; cc++) {
      u16x4 u = *reinterpret_cast<const u16x4*>(&zt[row][cc * 256 + lane * 4]);
#pragma unroll
      for (int i = 0; i < 4; i++) v[cc * 4 + i] = bfu2f(u[i]);
    }
    float sm = 0.f;
#pragma unroll
    for (int i = 0; i < 12; i++) sm += v[i];
#pragma unroll
    for (int m = 1; m < 64; m <<= 1) sm += __shfl_xor(sm, m);
    float mean = sm * (1.0f / 768.0f);
    float q = 0.f;
#pragma unroll
    for (int i = 0; i < 12; i++) { float d = v[i] - mean; q += d * d; }
#pragma unroll
    for (int m = 1; m < 64; m <<= 1) q += __shfl_xor(q, m);
    float rstd = rsqrtf(q * (1.0f / 768.0f) + 1e-5f);
    __hip_bfloat16* orow = h1 + ((size_t)b * SL + tstart + row) * HD;
#pragma unroll
    for (int cc = 0; cc < 3; cc++) {
      int j0 = cc * 256 + lane * 4;
      u16x4 o;
#pragma unroll
      for (int i = 0; i < 4; i++)
        o[i] = f2bfu((v[cc * 4 + i] - mean) * rstd * scale[j0 + i] + bias[j0 + i]);
      *reinterpret_cast<u16x4*>(orow + j0) = o;
    }
  }
}

// ---------------------------------------------------------------------------
// Counted-vmcnt pipelined MFMA GEMM (r12 schedule — best known).
// BM=128, 4 waves (256 thr), BK=64, 2 LDS buffers, 2 blocks/CU.
// Per K-step: vmcnt(L) [tile t's own 8|7 loads done; t+1's in flight] ->
//   s_barrier -> ds_read ALL frags of t to regs -> lgkmcnt(0) -> s_barrier ->
//   stage(t+2) into just-read buffer -> all MFMAs.
// T2 slot-XOR swizzle: LDS [rows][64] (128B pitch), linear dest,
// inverse-swizzled global src slot (l&7)^(l>>3); read slot (kk*4+kg)^(lr&7).
// C[M,N] = act(A[M,K] @ Bt[N,K]^T + bias) [+ R], bf16 out.
// ---------------------------------------------------------------------------
template <int BN, int ACT, int RADD>
__global__ __launch_bounds__(256, 2) void gemm_mfma_kernel(
    const __hip_bfloat16* __restrict__ A,
    const __hip_bfloat16* __restrict__ Bt,
    const float* __restrict__ bias,
    const __hip_bfloat16* __restrict__ R,
    __hip_bfloat16* __restrict__ Cb,
    int M, int N, int K)
{
  constexpr int NF = BN / 32;               // N-frags per wave: 4 or 3
  constexpr int ABUF = 128 * 64;            // A buffer elems (16KB)
  constexpr int BBUF = BN * 64;             // B buffer elems (16/12KB)
  __shared__ __align__(16) __hip_bfloat16 As[2 * ABUF];
  __shared__ __align__(16) __hip_bfloat16 Bs[2 * BBUF];
  const int m0 = blockIdx.x * 128;
  const int n0 = blockIdx.y * BN;
  const int tid  = threadIdx.x;
  const int lane = tid & 63;
  const int w    = tid >> 6;                // wave 0..3
  const int wr   = w >> 1;                  // 0..1 (M half, 64 rows)
  const int wc   = w & 1;                   // 0..1 (N half)
  const int lr   = lane & 15;
  const int kg   = lane >> 4;               // 0..3

  f32x4 acc[4][NF];
#pragma unroll
  for (int i = 0; i < 4; i++)
#pragma unroll
    for (int j = 0; j < NF; j++) acc[i][j] = (f32x4){0.f, 0.f, 0.f, 0.f};

  // staging: pass = 256 thr x 16B = 32 rows x 128B. Wave w rows w*8..w*8+7.
  // lane l: row w*8 + l/8, LDS slot l%8, global k-slot (l%8)^(l/8).
  const int prow = lane >> 3;               // 0..7
  const int pslot = lane & 7;
  const int gslot = pslot ^ prow;
  const __hip_bfloat16* aS = A  + (size_t)(m0 + w * 8 + prow) * K + gslot * 8;
  const __hip_bfloat16* bS = Bt + (size_t)(n0 + w * 8 + prow) * K + gslot * 8;
  const size_t K32g = (size_t)32 * K;       // 32-row pass stride (global)
  const int ldsw = w << 9;                  // w*512 elems (8 rows x 64)

  // per-wave loads per stage: A 4 passes + B NF passes = 8 (BN=128) / 7 (96)
  auto stage = [&](int buf, int k0) {
    __hip_bfloat16* Ab = As + buf * ABUF + ldsw;
    __hip_bfloat16* Bb = Bs + buf * BBUF + ldsw;
    gl2lds16(Ab,         aS + k0);               // A rows 0-31
    gl2lds16(Ab + 2048,  aS + k0 + K32g);        // A rows 32-63
    gl2lds16(Ab + 4096,  aS + k0 + 2 * K32g);    // A rows 64-95
    gl2lds16(Ab + 6144,  aS + k0 + 3 * K32g);    // A rows 96-127
    gl2lds16(Bb,         bS + k0);               // B rows 0-31
    gl2lds16(Bb + 2048,  bS + k0 + K32g);        // B rows 32-63
    gl2lds16(Bb + 4096,  bS + k0 + 2 * K32g);    // B rows 64-95
    if constexpr (BN == 128)
      gl2lds16(Bb + 6144, bS + k0 + 3 * K32g);   // B rows 96-127
  };

  // read-side swizzled slots (per-lane constants)
  const int rx = lr & 7;
  const int arow = wr * 64 + lr;            // + i*16
  const int brow = wc * (BN / 2) + lr;      // + j*16

  const int nt = K >> 6;                    // BK=64 tiles (12 or 48)
  stage(0, 0);
  stage(1, 64);

  for (int t = 0; t < nt; ++t) {
    const int cur = t & 1;
    // counted wait: tile t's own loads done; tile t+1's stay in flight
    if (t == nt - 1) {
      asm volatile("s_waitcnt vmcnt(0)" ::: "memory");
    } else {
      if constexpr (BN == 128) asm volatile("s_waitcnt vmcnt(8)" ::: "memory");
      else                     asm volatile("s_waitcnt vmcnt(7)" ::: "memory");
    }
    asm volatile("s_barrier" ::: "memory");          // all waves: tile t ready

    const __hip_bfloat16* Ab = As + cur * ABUF;
    const __hip_bfloat16* Bb = Bs + cur * BBUF;
    bf16x8s af[2][4], bq[2][NF];
#pragma unroll
    for (int kk = 0; kk < 2; kk++) {
      const int sl = ((kk * 4 + kg) ^ rx) * 8;
#pragma unroll
      for (int i = 0; i < 4; i++)
        af[kk][i] = *reinterpret_cast<const bf16x8s*>(&Ab[(arow + i * 16) * 64 + sl]);
#pragma unroll
      for (int j = 0; j < NF; j++)
        bq[kk][j] = *reinterpret_cast<const bf16x8s*>(&Bb[(brow + j * 16) * 64 + sl]);
    }
    asm volatile("s_waitcnt lgkmcnt(0)" ::: "memory");  // frags in regs
    asm volatile("s_barrier" ::: "memory");             // all waves done reading

    if (t + 2 < nt) stage(cur, (t + 2) << 6);  // overwrite just-read buffer

#pragma unroll
    for (int kk = 0; kk < 2; kk++)
#pragma unroll
      for (int i = 0; i < 4; i++)
#pragma unroll
        for (int j = 0; j < NF; j++)
          acc[i][j] = __builtin_amdgcn_mfma_f32_16x16x32_bf16(
              af[kk][i], bq[kk][j], acc[i][j], 0, 0, 0);
  }

#pragma unroll
  for (int i = 0; i < 4; i++)
#pragma unroll
    for (int j = 0; j < NF; j++) {
      int col = n0 + wc * (BN / 2) + j * 16 + lr;
      float bv = bias[col];
#pragma unroll
      for (int r = 0; r < 4; r++) {
        int row = m0 + wr * 64 + i * 16 + kg * 4 + r;
        float v = acc[i][j][r] + bv;
        if (ACT == 1) v = 1.f / (1.f + __expf(-v));
        else if (ACT == 2) {
          float x = v;
          float z = 1.5957691216057308f * (x + 0.044715f * x * x * x);
          v = x / (1.f + __expf(-z));
        }
        if (RADD) v += __bfloat162float(R[(size_t)row * N + col]);
        Cb[(size_t)row * N + col] = __float2bfloat16(v);
      }
    }
}

// ---------------------------------------------------------------------------
extern "C" void kernel_launch(void* const* d_in, const int* in_sizes, int n_in,
                              void* d_out, int out_size, void* d_ws, size_t ws_size,
                              hipStream_t stream)
{
  const int*   ids  = (const int*)d_in[0];
  const float* wemb = (const float*)d_in[1];
  const float* pemb = (const float*)d_in[2];
  const float* elns = (const float*)d_in[3];
  const float* elnb = (const float*)d_in[4];
  const float* retW = (const float*)d_in[5];
  const float* retb = (const float*)d_in[6];
  const float* ln1s = (const float*)d_in[7];
  const float* ln1b = (const float*)d_in[8];
  const float* W1   = (const float*)d_in[9];
  const float* b1   = (const float*)d_in[10];
  const float* W2   = (const float*)d_in[11];
  const float* b2   = (const float*)d_in[12];
  const float* ln2s = (const float*)d_in[13];
  const float* ln2b = (const float*)d_in[14];
  const float* fins = (const float*)d_in[15];
  const float* finb = (const float*)d_in[16];
  float* out = (float*)d_out;

  char* ws = (char*)d_ws;
  size_t off = 0;
  __hip_bfloat16* retWt = (__hip_bfloat16*)(ws + off); off += (size_t)NL * HD * HD * 2;
  __hip_bfloat16* W1t   = (__hip_bfloat16*)(ws + off); off += (size_t)NL * HD * ID * 2;
  __hip_bfloat16* W2t   = (__hip_bfloat16*)(ws + off); off += (size_t)NL * ID * HD * 2;
  __hip_bfloat16* hb    = (__hip_bfloat16*)(ws + off); off += (size_t)ROWS * HD * 2;  // residual h
  __hip_bfloat16* h1b   = (__hip_bfloat16*)(ws + off); off += (size_t)ROWS * HD * 2;  // h1
  __hip_bfloat16* yb    = (__hip_bfloat16*)(ws + off); off += (size_t)ROWS * HD * 2;  // h1+ffn2
  __hip_bfloat16* gb    = (__hip_bfloat16*)(ws + off); off += (size_t)ROWS * ID * 2;  // s / gelu out
  __hip_bfloat16* sb = gb;   // sigmoid out aliases gb (consumed before FFN1 rewrites)

  dim3 tb(32, 8);
  transpose_bf16_kernel<<<dim3(HD/32, HD/32, NL), tb, 0, stream>>>(retW, retWt, HD, HD);
  transpose_bf16_kernel<<<dim3(ID/32, HD/32, NL), tb, 0, stream>>>(W1, W1t, HD, ID);
  transpose_bf16_kernel<<<dim3(HD/32, ID/32, NL), tb, 0, stream>>>(W2, W2t, ID, HD);

  embed_ln_kernel<<<ROWS/4, 256, 0, stream>>>(ids, wemb, pemb, elns, elnb, hb);

  for (int l = 0; l < NL; l++) {
    // s = sigmoid(h @ retW + rb) -> sb (bf16). BN=96 (512 blocks = 2/CU)
    gemm_mfma_kernel<96, 1, 0><<<dim3(ROWS/128, HD/96), 256, 0, stream>>>(
        hb, retWt + (size_t)l * HD * HD, retb + (size_t)l * HD,
        nullptr, sb, ROWS, HD, HD);
    // h1 = LN(h + retention(s))  [fused scan+LN, no z round-trip]
    scan_ln_kernel<<<NB * (SL/32), 768, 0, stream>>>(sb, hb,
        ln1s + (size_t)l * HD, ln1b + (size_t)l * HD, h1b);
    // g = gelu(h1 @ W1 + b1) -> gb (bf16). BN=128 (1536 blocks)
    gemm_mfma_kernel<128, 2, 0><<<dim3(ROWS/128, ID/128), 256, 0, stream>>>(
        h1b, W1t + (size_t)l * ID * HD, b1 + (size_t)l * ID,
        nullptr, gb, ROWS, ID, HD);
    // y = h1 + (g @ W2 + b2) -> yb (bf16). BN=96 (512 blocks = 2/CU)
    gemm_mfma_kernel<96, 0, 1><<<dim3(ROWS/128, HD/96), 256, 0, stream>>>(
        gb, W2t + (size_t)l * HD * ID, b2 + (size_t)l * HD,
        h1b, yb, ROWS, HD, ID);
    // h = LN(y)
    ln_row_kernel<0><<<ROWS/4, 256, 0, stream>>>(yb,
        ln2s + (size_t)l * HD, ln2b + (size_t)l * HD, hb, nullptr);
  }
  // final LN -> d_out (f32)
  ln_row_kernel<1><<<ROWS/4, 256, 0, stream>>>(hb, fins, finb, nullptr, out);
}

// Round 18
// 561.421 us; speedup vs baseline: 1.0715x; 1.0066x over previous
//
#include <hip/hip_runtime.h>
#include <hip/hip_bf16.h>
#include <cstdint>
#include <cstddef>

// Problem dims
#define HD   768
#define ID   3072
#define NB   4
#define SL   2048
#define NL   4
#define ROWS (NB*SL)   // 8192

typedef __attribute__((ext_vector_type(8))) short bf16x8s;
typedef __attribute__((ext_vector_type(4))) float f32x4;
typedef __attribute__((ext_vector_type(4))) unsigned short u16x4;

typedef __attribute__((address_space(1))) const unsigned int g_as1_u32;
typedef __attribute__((address_space(3))) unsigned int lds_as3_u32;

// async 16B/lane global->LDS copy (wave-uniform LDS base + lane*16)
__device__ __forceinline__ void gl2lds16(__hip_bfloat16* l, const __hip_bfloat16* g) {
  __builtin_amdgcn_global_load_lds((g_as1_u32*)g, (lds_as3_u32*)l, 16, 0, 0);
}

__device__ __forceinline__ float bfu2f(unsigned short u) {
  return __uint_as_float((unsigned int)u << 16);
}
__device__ __forceinline__ unsigned short f2bfu(float f) {
  __hip_bfloat16 h = __float2bfloat16(f);
  return *reinterpret_cast<unsigned short*>(&h);
}

// ---------------------------------------------------------------------------
// Wave-per-row LayerNorm: block=256 (4 waves), wave w does row blockIdx*4+w.
// ---------------------------------------------------------------------------
template <int OUTF32>
__global__ __launch_bounds__(256) void ln_row_kernel(
    const __hip_bfloat16* __restrict__ x,
    const float* __restrict__ scale, const float* __restrict__ bias,
    __hip_bfloat16* __restrict__ ob, float* __restrict__ of)
{
  const int w = threadIdx.x >> 6, lane = threadIdx.x & 63;
  const size_t row = (size_t)blockIdx.x * 4 + w;
  const __hip_bfloat16* xr = x + row * HD;
  float v[12];
#pragma unroll
  for (int c = 0; c < 3; c++) {
    u16x4 u = *reinterpret_cast<const u16x4*>(xr + c * 256 + lane * 4);
#pragma unroll
    for (int i = 0; i < 4; i++) v[c * 4 + i] = bfu2f(u[i]);
  }
  float s = 0.f;
#pragma unroll
  for (int i = 0; i < 12; i++) s += v[i];
#pragma unroll
  for (int m = 1; m < 64; m <<= 1) s += __shfl_xor(s, m);
  float mean = s * (1.0f / 768.0f);
  float q = 0.f;
#pragma unroll
  for (int i = 0; i < 12; i++) { float d = v[i] - mean; q += d * d; }
#pragma unroll
  for (int m = 1; m < 64; m <<= 1) q += __shfl_xor(q, m);
  float rstd = rsqrtf(q * (1.0f / 768.0f) + 1e-5f);
#pragma unroll
  for (int c = 0; c < 3; c++) {
    int j0 = c * 256 + lane * 4;
    if (OUTF32) {
      f32x4 o;
#pragma unroll
      for (int i = 0; i < 4; i++)
        o[i] = (v[c * 4 + i] - mean) * rstd * scale[j0 + i] + bias[j0 + i];
      *reinterpret_cast<f32x4*>(of + row * HD + j0) = o;
    } else {
      u16x4 o;
#pragma unroll
      for (int i = 0; i < 4; i++)
        o[i] = f2bfu((v[c * 4 + i] - mean) * rstd * scale[j0 + i] + bias[j0 + i]);
      *reinterpret_cast<u16x4*>(ob + row * HD + j0) = o;
    }
  }
}

// embedding gather + pos add + LN (wave-per-row), writes bf16
__global__ __launch_bounds__(256) void embed_ln_kernel(
    const int* __restrict__ ids, const float* __restrict__ wemb,
    const float* __restrict__ pemb,
    const float* __restrict__ scale, const float* __restrict__ bias,
    __hip_bfloat16* __restrict__ ob)
{
  const int w = threadIdx.x >> 6, lane = threadIdx.x & 63;
  const size_t row = (size_t)blockIdx.x * 4 + w;
  const int t = (int)(row & (SL - 1));
  const int id = ids[row];
  float v[12];
#pragma unroll
  for (int c = 0; c < 3; c++) {
    int j0 = c * 256 + lane * 4;
    f32x4 a = *reinterpret_cast<const f32x4*>(wemb + (size_t)id * HD + j0);
    f32x4 p = *reinterpret_cast<const f32x4*>(pemb + (size_t)t * HD + j0);
#pragma unroll
    for (int i = 0; i < 4; i++) v[c * 4 + i] = a[i] + p[i];
  }
  float s = 0.f;
#pragma unroll
  for (int i = 0; i < 12; i++) s += v[i];
#pragma unroll
  for (int m = 1; m < 64; m <<= 1) s += __shfl_xor(s, m);
  float mean = s * (1.0f / 768.0f);
  float q = 0.f;
#pragma unroll
  for (int i = 0; i < 12; i++) { float d = v[i] - mean; q += d * d; }
#pragma unroll
  for (int m = 1; m < 64; m <<= 1) q += __shfl_xor(q, m);
  float rstd = rsqrtf(q * (1.0f / 768.0f) + 1e-5f);
#pragma unroll
  for (int c = 0; c < 3; c++) {
    int j0 = c * 256 + lane * 4;
    u16x4 o;
#pragma unroll
    for (int i = 0; i < 4; i++)
      o[i] = f2bfu((v[c * 4 + i] - mean) * rstd * scale[j0 + i] + bias[j0 + i]);
    *reinterpret_cast<u16x4*>(ob + row * HD + j0) = o;
  }
}

// ---------------------------------------------------------------------------
// Weight transpose + f32->bf16: in [K][N] f32 -> out [N][K] bf16, grid.z = layer
// ---------------------------------------------------------------------------
__global__ __launch_bounds__(256) void transpose_bf16_kernel(
    const float* __restrict__ in, __hip_bfloat16* __restrict__ out, int K, int N)
{
  __shared__ float tile[32][33];
  const float* inp = in + (size_t)blockIdx.z * K * N;
  __hip_bfloat16* outp = out + (size_t)blockIdx.z * K * N;
  int n0 = blockIdx.x * 32, k0 = blockIdx.y * 32;
  int tx = threadIdx.x, ty = threadIdx.y;   // (32, 8)
#pragma unroll
  for (int i = 0; i < 4; i++)
    tile[ty + i * 8][tx] = inp[(size_t)(k0 + ty + i * 8) * N + n0 + tx];
  __syncthreads();
#pragma unroll
  for (int i = 0; i < 4; i++)
    outp[(size_t)(n0 + ty + i * 8) * K + k0 + tx] = __float2bfloat16(tile[tx][ty + i * 8]);
}

// ---------------------------------------------------------------------------
// Fused retention scan + residual + LN1.
// Block (b, chunk of 32 timesteps), 768 threads (12 waves), 1 column/thread.
// Phase 1: 64-step warm-up (0.5^64 -> exact) + 32 steps z = h + r -> LDS.
// Phase 2: wave-per-row LN over the 32x768 LDS tile -> h1 (bf16).
// ---------------------------------------------------------------------------
__global__ __launch_bounds__(768) void scan_ln_kernel(
    const __hip_bfloat16* __restrict__ s,
    const __hip_bfloat16* __restrict__ h,
    const float* __restrict__ scale, const float* __restrict__ bias,
    __hip_bfloat16* __restrict__ h1)
{
  __shared__ __hip_bfloat16 zt[32][HD];     // 48 KB
  const int col = threadIdx.x;              // 0..767
  const int nchunk = SL / 32;               // 64
  const int c = blockIdx.x & (nchunk - 1);
  const int b = blockIdx.x / nchunk;
  const int tstart = c * 32;
  int t0 = tstart - 64; if (t0 < 0) t0 = 0;
  const __hip_bfloat16* sp = s + (size_t)b * SL * HD + col;
  const __hip_bfloat16* hp = h + (size_t)b * SL * HD + col;
  float acc = 0.f;
#pragma unroll 8
  for (int t = t0; t < tstart; ++t)
    acc = 0.5f * (__bfloat162float(sp[(size_t)t * HD]) + acc);
#pragma unroll 8
  for (int tt = 0; tt < 32; ++tt) {
    int t = tstart + tt;
    acc = 0.5f * (__bfloat162float(sp[(size_t)t * HD]) + acc);
    zt[tt][col] = __float2bfloat16(acc + __bfloat162float(hp[(size_t)t * HD]));
  }
  __syncthreads();
  // LN phase: 12 waves, wave wv handles rows wv, wv+12, wv+24 (<32)
  const int wv = threadIdx.x >> 6, lane = threadIdx.x & 63;
  for (int row = wv; row < 32; row += 12) {
    float v[12];
#pragma unroll
    for (int cc = 0; cc < 3; cc++) {
      u16x4 u = *reinterpret_cast<const u16x4*>(&zt[row][cc * 256 + lane * 4]);
#pragma unroll
      for (int i = 0; i < 4; i++) v[cc * 4 + i] = bfu2f(u[i]);
    }
    float sm = 0.f;
#pragma unroll
    for (int i = 0; i < 12; i++) sm += v[i];
#pragma unroll
    for (int m = 1; m < 64; m <<= 1) sm += __shfl_xor(sm, m);
    float mean = sm * (1.0f / 768.0f);
    float q = 0.f;
#pragma unroll
    for (int i = 0; i < 12; i++) { float d = v[i] - mean; q += d * d; }
#pragma unroll
    for (int m = 1; m < 64; m <<= 1) q += __shfl_xor(q, m);
    float rstd = rsqrtf(q * (1.0f / 768.0f) + 1e-5f);
    __hip_bfloat16* orow = h1 + ((size_t)b * SL + tstart + row) * HD;
#pragma unroll
    for (int cc = 0; cc < 3; cc++) {
      int j0 = cc * 256 + lane * 4;
      u16x4 o;
#pragma unroll
      for (int i = 0; i < 4; i++)
        o[i] = f2bfu((v[cc * 4 + i] - mean) * rstd * scale[j0 + i] + bias[j0 + i]);
      *reinterpret_cast<u16x4*>(orow + j0) = o;
    }
  }
}

// ---------------------------------------------------------------------------
// Counted-vmcnt pipelined MFMA GEMM (r12 schedule) + coalesced LDS epilogue.
// BM=128, 4 waves (256 thr), BK=64, 2 LDS buffers, 2 blocks/CU.
// K-loop identical to r12/r17. Epilogue: dump activated tile to LDS at
// padded stride BN+8 (2-way banks = free), syncthreads, then read back as
// 16B chunks -> fully coalesced global_store_dwordx4 (256B runs per 16
// lanes) instead of 64 scalar short-stores/thread.
// C[M,N] = act(A[M,K] @ Bt[N,K]^T + bias) [+ R], bf16 out.
// ---------------------------------------------------------------------------
template <int BN, int ACT, int RADD>
__global__ __launch_bounds__(256, 2) void gemm_mfma_kernel(
    const __hip_bfloat16* __restrict__ A,
    const __hip_bfloat16* __restrict__ Bt,
    const float* __restrict__ bias,
    const __hip_bfloat16* __restrict__ R,
    __hip_bfloat16* __restrict__ Cb,
    int M, int N, int K)
{
  constexpr int NF = BN / 32;               // N-frags per wave: 4 or 3
  constexpr int ABUF = 128 * 64;            // A buffer elems (16KB)
  constexpr int BBUF = BN * 64;             // B buffer elems (16/12KB)
  constexpr int CP = BN + 8;                // padded C-tile stride (elems)
  static_assert(128 * CP <= 2 * ABUF + 2 * BBUF, "C tile must fit in smem");
  __shared__ __align__(16) __hip_bfloat16 smem[2 * ABUF + 2 * BBUF];
  __hip_bfloat16* As = smem;
  __hip_bfloat16* Bs = smem + 2 * ABUF;
  const int m0 = blockIdx.x * 128;
  const int n0 = blockIdx.y * BN;
  const int tid  = threadIdx.x;
  const int lane = tid & 63;
  const int w    = tid >> 6;                // wave 0..3
  const int wr   = w >> 1;                  // 0..1 (M half, 64 rows)
  const int wc   = w & 1;                   // 0..1 (N half)
  const int lr   = lane & 15;
  const int kg   = lane >> 4;               // 0..3

  f32x4 acc[4][NF];
#pragma unroll
  for (int i = 0; i < 4; i++)
#pragma unroll
    for (int j = 0; j < NF; j++) acc[i][j] = (f32x4){0.f, 0.f, 0.f, 0.f};

  // staging: pass = 256 thr x 16B = 32 rows x 128B. Wave w rows w*8..w*8+7.
  // lane l: row w*8 + l/8, LDS slot l%8, global k-slot (l%8)^(l/8).
  const int prow = lane >> 3;               // 0..7
  const int pslot = lane & 7;
  const int gslot = pslot ^ prow;
  const __hip_bfloat16* aS = A  + (size_t)(m0 + w * 8 + prow) * K + gslot * 8;
  const __hip_bfloat16* bS = Bt + (size_t)(n0 + w * 8 + prow) * K + gslot * 8;
  const size_t K32g = (size_t)32 * K;       // 32-row pass stride (global)
  const int ldsw = w << 9;                  // w*512 elems (8 rows x 64)

  // per-wave loads per stage: A 4 passes + B NF passes = 8 (BN=128) / 7 (96)
  auto stage = [&](int buf, int k0) {
    __hip_bfloat16* Ab = As + buf * ABUF + ldsw;
    __hip_bfloat16* Bb = Bs + buf * BBUF + ldsw;
    gl2lds16(Ab,         aS + k0);               // A rows 0-31
    gl2lds16(Ab + 2048,  aS + k0 + K32g);        // A rows 32-63
    gl2lds16(Ab + 4096,  aS + k0 + 2 * K32g);    // A rows 64-95
    gl2lds16(Ab + 6144,  aS + k0 + 3 * K32g);    // A rows 96-127
    gl2lds16(Bb,         bS + k0);               // B rows 0-31
    gl2lds16(Bb + 2048,  bS + k0 + K32g);        // B rows 32-63
    gl2lds16(Bb + 4096,  bS + k0 + 2 * K32g);    // B rows 64-95
    if constexpr (BN == 128)
      gl2lds16(Bb + 6144, bS + k0 + 3 * K32g);   // B rows 96-127
  };

  // read-side swizzled slots (per-lane constants)
  const int rx = lr & 7;
  const int arow = wr * 64 + lr;            // + i*16
  const int brow = wc * (BN / 2) + lr;      // + j*16

  const int nt = K >> 6;                    // BK=64 tiles (12 or 48)
  stage(0, 0);
  stage(1, 64);

  for (int t = 0; t < nt; ++t) {
    const int cur = t & 1;
    // counted wait: tile t's own loads done; tile t+1's stay in flight
    if (t == nt - 1) {
      asm volatile("s_waitcnt vmcnt(0)" ::: "memory");
    } else {
      if constexpr (BN == 128) asm volatile("s_waitcnt vmcnt(8)" ::: "memory");
      else                     asm volatile("s_waitcnt vmcnt(7)" ::: "memory");
    }
    asm volatile("s_barrier" ::: "memory");          // all waves: tile t ready

    const __hip_bfloat16* Ab = As + cur * ABUF;
    const __hip_bfloat16* Bb = Bs + cur * BBUF;
    bf16x8s af[2][4], bq[2][NF];
#pragma unroll
    for (int kk = 0; kk < 2; kk++) {
      const int sl = ((kk * 4 + kg) ^ rx) * 8;
#pragma unroll
      for (int i = 0; i < 4; i++)
        af[kk][i] = *reinterpret_cast<const bf16x8s*>(&Ab[(arow + i * 16) * 64 + sl]);
#pragma unroll
      for (int j = 0; j < NF; j++)
        bq[kk][j] = *reinterpret_cast<const bf16x8s*>(&Bb[(brow + j * 16) * 64 + sl]);
    }
    asm volatile("s_waitcnt lgkmcnt(0)" ::: "memory");  // frags in regs
    asm volatile("s_barrier" ::: "memory");             // all waves done reading

    if (t + 2 < nt) stage(cur, (t + 2) << 6);  // overwrite just-read buffer

#pragma unroll
    for (int kk = 0; kk < 2; kk++)
#pragma unroll
      for (int i = 0; i < 4; i++)
#pragma unroll
        for (int j = 0; j < NF; j++)
          acc[i][j] = __builtin_amdgcn_mfma_f32_16x16x32_bf16(
              af[kk][i], bq[kk][j], acc[i][j], 0, 0, 0);
  }

  // ---- epilogue: dump activated tile to LDS (stage buffers are dead:
  // all reads drained before the final barrier; vmcnt(0) drained) ----
  __hip_bfloat16* Ct = smem;
#pragma unroll
  for (int i = 0; i < 4; i++)
#pragma unroll
    for (int j = 0; j < NF; j++) {
      int cl = wc * (BN / 2) + j * 16 + lr;      // col within tile
      float bv = bias[n0 + cl];
#pragma unroll
      for (int r = 0; r < 4; r++) {
        int rl = wr * 64 + i * 16 + kg * 4 + r;  // row within tile
        float v = acc[i][j][r] + bv;
        if (ACT == 1) v = 1.f / (1.f + __expf(-v));
        else if (ACT == 2) {
          float x = v;
          float z = 1.5957691216057308f * (x + 0.044715f * x * x * x);
          v = x / (1.f + __expf(-z));
        }
        if (RADD) v += __bfloat162float(R[(size_t)(m0 + rl) * N + n0 + cl]);
        Ct[rl * CP + cl] = __float2bfloat16(v);
      }
    }
  __syncthreads();

  // coalesced write-out: 16B chunks, 16 consecutive lanes = 256B runs
  constexpr int CPR = BN / 8;               // 16B chunks per row (16 or 12)
  constexpr int NPASS = 128 * CPR / 256;    // 8 or 6 passes
#pragma unroll
  for (int p = 0; p < NPASS; ++p) {
    int idx = p * 256 + tid;
    int row = idx / CPR;
    int ch  = idx - row * CPR;
    uint4 d = *reinterpret_cast<const uint4*>(&Ct[row * CP + ch * 8]);
    *reinterpret_cast<uint4*>(&Cb[(size_t)(m0 + row) * N + n0 + ch * 8]) = d;
  }
}

// ---------------------------------------------------------------------------
extern "C" void kernel_launch(void* const* d_in, const int* in_sizes, int n_in,
                              void* d_out, int out_size, void* d_ws, size_t ws_size,
                              hipStream_t stream)
{
  const int*   ids  = (const int*)d_in[0];
  const float* wemb = (const float*)d_in[1];
  const float* pemb = (const float*)d_in[2];
  const float* elns = (const float*)d_in[3];
  const float* elnb = (const float*)d_in[4];
  const float* retW = (const float*)d_in[5];
  const float* retb = (const float*)d_in[6];
  const float* ln1s = (const float*)d_in[7];
  const float* ln1b = (const float*)d_in[8];
  const float* W1   = (const float*)d_in[9];
  const float* b1   = (const float*)d_in[10];
  const float* W2   = (const float*)d_in[11];
  const float* b2   = (const float*)d_in[12];
  const float* ln2s = (const float*)d_in[13];
  const float* ln2b = (const float*)d_in[14];
  const float* fins = (const float*)d_in[15];
  const float* finb = (const float*)d_in[16];
  float* out = (float*)d_out;

  char* ws = (char*)d_ws;
  size_t off = 0;
  __hip_bfloat16* retWt = (__hip_bfloat16*)(ws + off); off += (size_t)NL * HD * HD * 2;
  __hip_bfloat16* W1t   = (__hip_bfloat16*)(ws + off); off += (size_t)NL * HD * ID * 2;
  __hip_bfloat16* W2t   = (__hip_bfloat16*)(ws + off); off += (size_t)NL * ID * HD * 2;
  __hip_bfloat16* hb    = (__hip_bfloat16*)(ws + off); off += (size_t)ROWS * HD * 2;  // residual h
  __hip_bfloat16* h1b   = (__hip_bfloat16*)(ws + off); off += (size_t)ROWS * HD * 2;  // h1
  __hip_bfloat16* yb    = (__hip_bfloat16*)(ws + off); off += (size_t)ROWS * HD * 2;  // h1+ffn2
  __hip_bfloat16* gb    = (__hip_bfloat16*)(ws + off); off += (size_t)ROWS * ID * 2;  // s / gelu out
  __hip_bfloat16* sb = gb;   // sigmoid out aliases gb (consumed before FFN1 rewrites)

  dim3 tb(32, 8);
  transpose_bf16_kernel<<<dim3(HD/32, HD/32, NL), tb, 0, stream>>>(retW, retWt, HD, HD);
  transpose_bf16_kernel<<<dim3(ID/32, HD/32, NL), tb, 0, stream>>>(W1, W1t, HD, ID);
  transpose_bf16_kernel<<<dim3(HD/32, ID/32, NL), tb, 0, stream>>>(W2, W2t, ID, HD);

  embed_ln_kernel<<<ROWS/4, 256, 0, stream>>>(ids, wemb, pemb, elns, elnb, hb);

  for (int l = 0; l < NL; l++) {
    // s = sigmoid(h @ retW + rb) -> sb (bf16). BN=96 (512 blocks = 2/CU)
    gemm_mfma_kernel<96, 1, 0><<<dim3(ROWS/128, HD/96), 256, 0, stream>>>(
        hb, retWt + (size_t)l * HD * HD, retb + (size_t)l * HD,
        nullptr, sb, ROWS, HD, HD);
    // h1 = LN(h + retention(s))  [fused scan+LN, no z round-trip]
    scan_ln_kernel<<<NB * (SL/32), 768, 0, stream>>>(sb, hb,
        ln1s + (size_t)l * HD, ln1b + (size_t)l * HD, h1b);
    // g = gelu(h1 @ W1 + b1) -> gb (bf16). BN=128 (1536 blocks)
    gemm_mfma_kernel<128, 2, 0><<<dim3(ROWS/128, ID/128), 256, 0, stream>>>(
        h1b, W1t + (size_t)l * ID * HD, b1 + (size_t)l * ID,
        nullptr, gb, ROWS, ID, HD);
    // y = h1 + (g @ W2 + b2) -> yb (bf16). BN=96 (512 blocks = 2/CU)
    gemm_mfma_kernel<96, 0, 1><<<dim3(ROWS/128, HD/96), 256, 0, stream>>>(
        gb, W2t + (size_t)l * HD * ID, b2 + (size_t)l * HD,
        h1b, yb, ROWS, HD, ID);
    // h = LN(y)
    ln_row_kernel<0><<<ROWS/4, 256, 0, stream>>>(yb,
        ln2s + (size_t)l * HD, ln2b + (size_t)l * HD, hb, nullptr);
  }
  // final LN -> d_out (f32)
  ln_row_kernel<1><<<ROWS/4, 256, 0, stream>>>(hb, fins, finb, nullptr, out);
}

// Round 19
// 548.865 us; speedup vs baseline: 1.0960x; 1.0229x over previous
//
#include <hip/hip_runtime.h>
#include <hip/hip_bf16.h>
#include <cstdint>
#include <cstddef>

// Problem dims
#define HD   768
#define ID   3072
#define NB   4
#define SL   2048
#define NL   4
#define ROWS (NB*SL)   // 8192

typedef __attribute__((ext_vector_type(8))) short bf16x8s;
typedef __attribute__((ext_vector_type(4))) float f32x4;
typedef __attribute__((ext_vector_type(4))) unsigned short u16x4;

typedef __attribute__((address_space(1))) const unsigned int g_as1_u32;
typedef __attribute__((address_space(3))) unsigned int lds_as3_u32;

// async 16B/lane global->LDS copy (wave-uniform LDS base + lane*16)
__device__ __forceinline__ void gl2lds16(__hip_bfloat16* l, const __hip_bfloat16* g) {
  __builtin_amdgcn_global_load_lds((g_as1_u32*)g, (lds_as3_u32*)l, 16, 0, 0);
}

__device__ __forceinline__ float bfu2f(unsigned short u) {
  return __uint_as_float((unsigned int)u << 16);
}
__device__ __forceinline__ unsigned short f2bfu(float f) {
  __hip_bfloat16 h = __float2bfloat16(f);
  return *reinterpret_cast<unsigned short*>(&h);
}

// ---------------------------------------------------------------------------
// Wave-per-row LayerNorm: block=256 (4 waves), wave w does row blockIdx*4+w.
// ---------------------------------------------------------------------------
template <int OUTF32>
__global__ __launch_bounds__(256) void ln_row_kernel(
    const __hip_bfloat16* __restrict__ x,
    const float* __restrict__ scale, const float* __restrict__ bias,
    __hip_bfloat16* __restrict__ ob, float* __restrict__ of)
{
  const int w = threadIdx.x >> 6, lane = threadIdx.x & 63;
  const size_t row = (size_t)blockIdx.x * 4 + w;
  const __hip_bfloat16* xr = x + row * HD;
  float v[12];
#pragma unroll
  for (int c = 0; c < 3; c++) {
    u16x4 u = *reinterpret_cast<const u16x4*>(xr + c * 256 + lane * 4);
#pragma unroll
    for (int i = 0; i < 4; i++) v[c * 4 + i] = bfu2f(u[i]);
  }
  float s = 0.f;
#pragma unroll
  for (int i = 0; i < 12; i++) s += v[i];
#pragma unroll
  for (int m = 1; m < 64; m <<= 1) s += __shfl_xor(s, m);
  float mean = s * (1.0f / 768.0f);
  float q = 0.f;
#pragma unroll
  for (int i = 0; i < 12; i++) { float d = v[i] - mean; q += d * d; }
#pragma unroll
  for (int m = 1; m < 64; m <<= 1) q += __shfl_xor(q, m);
  float rstd = rsqrtf(q * (1.0f / 768.0f) + 1e-5f);
#pragma unroll
  for (int c = 0; c < 3; c++) {
    int j0 = c * 256 + lane * 4;
    if (OUTF32) {
      f32x4 o;
#pragma unroll
      for (int i = 0; i < 4; i++)
        o[i] = (v[c * 4 + i] - mean) * rstd * scale[j0 + i] + bias[j0 + i];
      *reinterpret_cast<f32x4*>(of + row * HD + j0) = o;
    } else {
      u16x4 o;
#pragma unroll
      for (int i = 0; i < 4; i++)
        o[i] = f2bfu((v[c * 4 + i] - mean) * rstd * scale[j0 + i] + bias[j0 + i]);
      *reinterpret_cast<u16x4*>(ob + row * HD + j0) = o;
    }
  }
}

// ---------------------------------------------------------------------------
// Fused LN2 + final LN (last layer only): out = LNf(bf16(LN2(y))).
// Keeps the exact rounding chain of the unfused pair (intermediate rounded
// to bf16), but skips the hb write+read (25 MB) and one dispatch.
// ---------------------------------------------------------------------------
__global__ __launch_bounds__(256) void ln2_final_kernel(
    const __hip_bfloat16* __restrict__ y,
    const float* __restrict__ s2, const float* __restrict__ b2,
    const float* __restrict__ fs, const float* __restrict__ fb,
    float* __restrict__ out)
{
  const int w = threadIdx.x >> 6, lane = threadIdx.x & 63;
  const size_t row = (size_t)blockIdx.x * 4 + w;
  const __hip_bfloat16* xr = y + row * HD;
  float v[12];
#pragma unroll
  for (int c = 0; c < 3; c++) {
    u16x4 u = *reinterpret_cast<const u16x4*>(xr + c * 256 + lane * 4);
#pragma unroll
    for (int i = 0; i < 4; i++) v[c * 4 + i] = bfu2f(u[i]);
  }
  float s = 0.f;
#pragma unroll
  for (int i = 0; i < 12; i++) s += v[i];
#pragma unroll
  for (int m = 1; m < 64; m <<= 1) s += __shfl_xor(s, m);
  float mean = s * (1.0f / 768.0f);
  float q = 0.f;
#pragma unroll
  for (int i = 0; i < 12; i++) { float d = v[i] - mean; q += d * d; }
#pragma unroll
  for (int m = 1; m < 64; m <<= 1) q += __shfl_xor(q, m);
  float rstd = rsqrtf(q * (1.0f / 768.0f) + 1e-5f);
  // LN2 result, rounded to bf16 exactly as the unfused path stored it
  float t[12];
#pragma unroll
  for (int c = 0; c < 3; c++) {
    int j0 = c * 256 + lane * 4;
#pragma unroll
    for (int i = 0; i < 4; i++)
      t[c * 4 + i] = bfu2f(f2bfu((v[c * 4 + i] - mean) * rstd * s2[j0 + i] + b2[j0 + i]));
  }
  // final LN over t
  float s2m = 0.f;
#pragma unroll
  for (int i = 0; i < 12; i++) s2m += t[i];
#pragma unroll
  for (int m = 1; m < 64; m <<= 1) s2m += __shfl_xor(s2m, m);
  float mean2 = s2m * (1.0f / 768.0f);
  float q2 = 0.f;
#pragma unroll
  for (int i = 0; i < 12; i++) { float d = t[i] - mean2; q2 += d * d; }
#pragma unroll
  for (int m = 1; m < 64; m <<= 1) q2 += __shfl_xor(q2, m);
  float rstd2 = rsqrtf(q2 * (1.0f / 768.0f) + 1e-5f);
#pragma unroll
  for (int c = 0; c < 3; c++) {
    int j0 = c * 256 + lane * 4;
    f32x4 o;
#pragma unroll
    for (int i = 0; i < 4; i++)
      o[i] = (t[c * 4 + i] - mean2) * rstd2 * fs[j0 + i] + fb[j0 + i];
    *reinterpret_cast<f32x4*>(out + row * HD + j0) = o;
  }
}

// embedding gather + pos add + LN (wave-per-row), writes bf16
__global__ __launch_bounds__(256) void embed_ln_kernel(
    const int* __restrict__ ids, const float* __restrict__ wemb,
    const float* __restrict__ pemb,
    const float* __restrict__ scale, const float* __restrict__ bias,
    __hip_bfloat16* __restrict__ ob)
{
  const int w = threadIdx.x >> 6, lane = threadIdx.x & 63;
  const size_t row = (size_t)blockIdx.x * 4 + w;
  const int t = (int)(row & (SL - 1));
  const int id = ids[row];
  float v[12];
#pragma unroll
  for (int c = 0; c < 3; c++) {
    int j0 = c * 256 + lane * 4;
    f32x4 a = *reinterpret_cast<const f32x4*>(wemb + (size_t)id * HD + j0);
    f32x4 p = *reinterpret_cast<const f32x4*>(pemb + (size_t)t * HD + j0);
#pragma unroll
    for (int i = 0; i < 4; i++) v[c * 4 + i] = a[i] + p[i];
  }
  float s = 0.f;
#pragma unroll
  for (int i = 0; i < 12; i++) s += v[i];
#pragma unroll
  for (int m = 1; m < 64; m <<= 1) s += __shfl_xor(s, m);
  float mean = s * (1.0f / 768.0f);
  float q = 0.f;
#pragma unroll
  for (int i = 0; i < 12; i++) { float d = v[i] - mean; q += d * d; }
#pragma unroll
  for (int m = 1; m < 64; m <<= 1) q += __shfl_xor(q, m);
  float rstd = rsqrtf(q * (1.0f / 768.0f) + 1e-5f);
#pragma unroll
  for (int c = 0; c < 3; c++) {
    int j0 = c * 256 + lane * 4;
    u16x4 o;
#pragma unroll
    for (int i = 0; i < 4; i++)
      o[i] = f2bfu((v[c * 4 + i] - mean) * rstd * scale[j0 + i] + bias[j0 + i]);
    *reinterpret_cast<u16x4*>(ob + row * HD + j0) = o;
  }
}

// ---------------------------------------------------------------------------
// Weight transpose + f32->bf16: in [K][N] f32 -> out [N][K] bf16, grid.z = layer
// ---------------------------------------------------------------------------
__global__ __launch_bounds__(256) void transpose_bf16_kernel(
    const float* __restrict__ in, __hip_bfloat16* __restrict__ out, int K, int N)
{
  __shared__ float tile[32][33];
  const float* inp = in + (size_t)blockIdx.z * K * N;
  __hip_bfloat16* outp = out + (size_t)blockIdx.z * K * N;
  int n0 = blockIdx.x * 32, k0 = blockIdx.y * 32;
  int tx = threadIdx.x, ty = threadIdx.y;   // (32, 8)
#pragma unroll
  for (int i = 0; i < 4; i++)
    tile[ty + i * 8][tx] = inp[(size_t)(k0 + ty + i * 8) * N + n0 + tx];
  __syncthreads();
#pragma unroll
  for (int i = 0; i < 4; i++)
    outp[(size_t)(n0 + ty + i * 8) * K + k0 + tx] = __float2bfloat16(tile[tx][ty + i * 8]);
}

// ---------------------------------------------------------------------------
// Fused retention scan + residual + LN1.
// Block (b, chunk of 32 timesteps), 768 threads (12 waves), 1 column/thread.
// Phase 1: 32-step warm-up (0.5^32 ~ 2e-10, far below bf16/f32 noise) +
// 32 steps z = h + r -> LDS. Phase 2: wave-per-row LN -> h1 (bf16).
// ---------------------------------------------------------------------------
__global__ __launch_bounds__(768) void scan_ln_kernel(
    const __hip_bfloat16* __restrict__ s,
    const __hip_bfloat16* __restrict__ h,
    const float* __restrict__ scale, const float* __restrict__ bias,
    __hip_bfloat16* __restrict__ h1)
{
  __shared__ __hip_bfloat16 zt[32][HD];     // 48 KB
  const int col = threadIdx.x;              // 0..767
  const int nchunk = SL / 32;               // 64
  const int c = blockIdx.x & (nchunk - 1);
  const int b = blockIdx.x / nchunk;
  const int tstart = c * 32;
  int t0 = tstart - 32; if (t0 < 0) t0 = 0;
  const __hip_bfloat16* sp = s + (size_t)b * SL * HD + col;
  const __hip_bfloat16* hp = h + (size_t)b * SL * HD + col;
  float acc = 0.f;
#pragma unroll 8
  for (int t = t0; t < tstart; ++t)
    acc = 0.5f * (__bfloat162float(sp[(size_t)t * HD]) + acc);
#pragma unroll 8
  for (int tt = 0; tt < 32; ++tt) {
    int t = tstart + tt;
    acc = 0.5f * (__bfloat162float(sp[(size_t)t * HD]) + acc);
    zt[tt][col] = __float2bfloat16(acc + __bfloat162float(hp[(size_t)t * HD]));
  }
  __syncthreads();
  // LN phase: 12 waves, wave wv handles rows wv, wv+12, wv+24 (<32)
  const int wv = threadIdx.x >> 6, lane = threadIdx.x & 63;
  for (int row = wv; row < 32; row += 12) {
    float v[12];
#pragma unroll
    for (int cc = 0; cc < 3; cc++) {
      u16x4 u = *reinterpret_cast<const u16x4*>(&zt[row][cc * 256 + lane * 4]);
#pragma unroll
      for (int i = 0; i < 4; i++) v[cc * 4 + i] = bfu2f(u[i]);
    }
    float sm = 0.f;
#pragma unroll
    for (int i = 0; i < 12; i++) sm += v[i];
#pragma unroll
    for (int m = 1; m < 64; m <<= 1) sm += __shfl_xor(sm, m);
    float mean = sm * (1.0f / 768.0f);
    float q = 0.f;
#pragma unroll
    for (int i = 0; i < 12; i++) { float d = v[i] - mean; q += d * d; }
#pragma unroll
    for (int m = 1; m < 64; m <<= 1) q += __shfl_xor(q, m);
    float rstd = rsqrtf(q * (1.0f / 768.0f) + 1e-5f);
    __hip_bfloat16* orow = h1 + ((size_t)b * SL + tstart + row) * HD;
#pragma unroll
    for (int cc = 0; cc < 3; cc++) {
      int j0 = cc * 256 + lane * 4;
      u16x4 o;
#pragma unroll
      for (int i = 0; i < 4; i++)
        o[i] = f2bfu((v[cc * 4 + i] - mean) * rstd * scale[j0 + i] + bias[j0 + i]);
      *reinterpret_cast<u16x4*>(orow + j0) = o;
    }
  }
}

// ---------------------------------------------------------------------------
// Counted-vmcnt pipelined MFMA GEMM (r12 schedule) + coalesced LDS epilogue.
// BM=128, 4 waves (256 thr), BK=64, 2 LDS buffers, 2 blocks/CU.
// ---------------------------------------------------------------------------
template <int BN, int ACT, int RADD>
__global__ __launch_bounds__(256, 2) void gemm_mfma_kernel(
    const __hip_bfloat16* __restrict__ A,
    const __hip_bfloat16* __restrict__ Bt,
    const float* __restrict__ bias,
    const __hip_bfloat16* __restrict__ R,
    __hip_bfloat16* __restrict__ Cb,
    int M, int N, int K)
{
  constexpr int NF = BN / 32;               // N-frags per wave: 4 or 3
  constexpr int ABUF = 128 * 64;            // A buffer elems (16KB)
  constexpr int BBUF = BN * 64;             // B buffer elems (16/12KB)
  constexpr int CP = BN + 8;                // padded C-tile stride (elems)
  static_assert(128 * CP <= 2 * ABUF + 2 * BBUF, "C tile must fit in smem");
  __shared__ __align__(16) __hip_bfloat16 smem[2 * ABUF + 2 * BBUF];
  __hip_bfloat16* As = smem;
  __hip_bfloat16* Bs = smem + 2 * ABUF;
  const int m0 = blockIdx.x * 128;
  const int n0 = blockIdx.y * BN;
  const int tid  = threadIdx.x;
  const int lane = tid & 63;
  const int w    = tid >> 6;                // wave 0..3
  const int wr   = w >> 1;                  // 0..1 (M half, 64 rows)
  const int wc   = w & 1;                   // 0..1 (N half)
  const int lr   = lane & 15;
  const int kg   = lane >> 4;               // 0..3

  f32x4 acc[4][NF];
#pragma unroll
  for (int i = 0; i < 4; i++)
#pragma unroll
    for (int j = 0; j < NF; j++) acc[i][j] = (f32x4){0.f, 0.f, 0.f, 0.f};

  // staging: pass = 256 thr x 16B = 32 rows x 128B. Wave w rows w*8..w*8+7.
  // lane l: row w*8 + l/8, LDS slot l%8, global k-slot (l%8)^(l/8).
  const int prow = lane >> 3;               // 0..7
  const int pslot = lane & 7;
  const int gslot = pslot ^ prow;
  const __hip_bfloat16* aS = A  + (size_t)(m0 + w * 8 + prow) * K + gslot * 8;
  const __hip_bfloat16* bS = Bt + (size_t)(n0 + w * 8 + prow) * K + gslot * 8;
  const size_t K32g = (size_t)32 * K;       // 32-row pass stride (global)
  const int ldsw = w << 9;                  // w*512 elems (8 rows x 64)

  // per-wave loads per stage: A 4 passes + B NF passes = 8 (BN=128) / 7 (96)
  auto stage = [&](int buf, int k0) {
    __hip_bfloat16* Ab = As + buf * ABUF + ldsw;
    __hip_bfloat16* Bb = Bs + buf * BBUF + ldsw;
    gl2lds16(Ab,         aS + k0);               // A rows 0-31
    gl2lds16(Ab + 2048,  aS + k0 + K32g);        // A rows 32-63
    gl2lds16(Ab + 4096,  aS + k0 + 2 * K32g);    // A rows 64-95
    gl2lds16(Ab + 6144,  aS + k0 + 3 * K32g);    // A rows 96-127
    gl2lds16(Bb,         bS + k0);               // B rows 0-31
    gl2lds16(Bb + 2048,  bS + k0 + K32g);        // B rows 32-63
    gl2lds16(Bb + 4096,  bS + k0 + 2 * K32g);    // B rows 64-95
    if constexpr (BN == 128)
      gl2lds16(Bb + 6144, bS + k0 + 3 * K32g);   // B rows 96-127
  };

  // read-side swizzled slots (per-lane constants)
  const int rx = lr & 7;
  const int arow = wr * 64 + lr;            // + i*16
  const int brow = wc * (BN / 2) + lr;      // + j*16

  const int nt = K >> 6;                    // BK=64 tiles (12 or 48)
  stage(0, 0);
  stage(1, 64);

  for (int t = 0; t < nt; ++t) {
    const int cur = t & 1;
    // counted wait: tile t's own loads done; tile t+1's stay in flight
    if (t == nt - 1) {
      asm volatile("s_waitcnt vmcnt(0)" ::: "memory");
    } else {
      if constexpr (BN == 128) asm volatile("s_waitcnt vmcnt(8)" ::: "memory");
      else                     asm volatile("s_waitcnt vmcnt(7)" ::: "memory");
    }
    asm volatile("s_barrier" ::: "memory");          // all waves: tile t ready

    const __hip_bfloat16* Ab = As + cur * ABUF;
    const __hip_bfloat16* Bb = Bs + cur * BBUF;
    bf16x8s af[2][4], bq[2][NF];
#pragma unroll
    for (int kk = 0; kk < 2; kk++) {
      const int sl = ((kk * 4 + kg) ^ rx) * 8;
#pragma unroll
      for (int i = 0; i < 4; i++)
        af[kk][i] = *reinterpret_cast<const bf16x8s*>(&Ab[(arow + i * 16) * 64 + sl]);
#pragma unroll
      for (int j = 0; j < NF; j++)
        bq[kk][j] = *reinterpret_cast<const bf16x8s*>(&Bb[(brow + j * 16) * 64 + sl]);
    }
    asm volatile("s_waitcnt lgkmcnt(0)" ::: "memory");  // frags in regs
    asm volatile("s_barrier" ::: "memory");             // all waves done reading

    if (t + 2 < nt) stage(cur, (t + 2) << 6);  // overwrite just-read buffer

#pragma unroll
    for (int kk = 0; kk < 2; kk++)
#pragma unroll
      for (int i = 0; i < 4; i++)
#pragma unroll
        for (int j = 0; j < NF; j++)
          acc[i][j] = __builtin_amdgcn_mfma_f32_16x16x32_bf16(
              af[kk][i], bq[kk][j], acc[i][j], 0, 0, 0);
  }

  // ---- epilogue: dump activated tile to LDS, then coalesced write-out ----
  __hip_bfloat16* Ct = smem;
#pragma unroll
  for (int i = 0; i < 4; i++)
#pragma unroll
    for (int j = 0; j < NF; j++) {
      int cl = wc * (BN / 2) + j * 16 + lr;      // col within tile
      float bv = bias[n0 + cl];
#pragma unroll
      for (int r = 0; r < 4; r++) {
        int rl = wr * 64 + i * 16 + kg * 4 + r;  // row within tile
        float v = acc[i][j][r] + bv;
        if (ACT == 1) v = 1.f / (1.f + __expf(-v));
        else if (ACT == 2) {
          float x = v;
          float z = 1.5957691216057308f * (x + 0.044715f * x * x * x);
          v = x / (1.f + __expf(-z));
        }
        if (RADD) v += __bfloat162float(R[(size_t)(m0 + rl) * N + n0 + cl]);
        Ct[rl * CP + cl] = __float2bfloat16(v);
      }
    }
  __syncthreads();

  // coalesced write-out: 16B chunks, 16 consecutive lanes = 256B runs
  constexpr int CPR = BN / 8;               // 16B chunks per row (16 or 12)
  constexpr int NPASS = 128 * CPR / 256;    // 8 or 6 passes
#pragma unroll
  for (int p = 0; p < NPASS; ++p) {
    int idx = p * 256 + tid;
    int row = idx / CPR;
    int ch  = idx - row * CPR;
    uint4 d = *reinterpret_cast<const uint4*>(&Ct[row * CP + ch * 8]);
    *reinterpret_cast<uint4*>(&Cb[(size_t)(m0 + row) * N + n0 + ch * 8]) = d;
  }
}

// ---------------------------------------------------------------------------
extern "C" void kernel_launch(void* const* d_in, const int* in_sizes, int n_in,
                              void* d_out, int out_size, void* d_ws, size_t ws_size,
                              hipStream_t stream)
{
  const int*   ids  = (const int*)d_in[0];
  const float* wemb = (const float*)d_in[1];
  const float* pemb = (const float*)d_in[2];
  const float* elns = (const float*)d_in[3];
  const float* elnb = (const float*)d_in[4];
  const float* retW = (const float*)d_in[5];
  const float* retb = (const float*)d_in[6];
  const float* ln1s = (const float*)d_in[7];
  const float* ln1b = (const float*)d_in[8];
  const float* W1   = (const float*)d_in[9];
  const float* b1   = (const float*)d_in[10];
  const float* W2   = (const float*)d_in[11];
  const float* b2   = (const float*)d_in[12];
  const float* ln2s = (const float*)d_in[13];
  const float* ln2b = (const float*)d_in[14];
  const float* fins = (const float*)d_in[15];
  const float* finb = (const float*)d_in[16];
  float* out = (float*)d_out;

  char* ws = (char*)d_ws;
  size_t off = 0;
  __hip_bfloat16* retWt = (__hip_bfloat16*)(ws + off); off += (size_t)NL * HD * HD * 2;
  __hip_bfloat16* W1t   = (__hip_bfloat16*)(ws + off); off += (size_t)NL * HD * ID * 2;
  __hip_bfloat16* W2t   = (__hip_bfloat16*)(ws + off); off += (size_t)NL * ID * HD * 2;
  __hip_bfloat16* hb    = (__hip_bfloat16*)(ws + off); off += (size_t)ROWS * HD * 2;  // residual h
  __hip_bfloat16* h1b   = (__hip_bfloat16*)(ws + off); off += (size_t)ROWS * HD * 2;  // h1
  __hip_bfloat16* yb    = (__hip_bfloat16*)(ws + off); off += (size_t)ROWS * HD * 2;  // h1+ffn2
  __hip_bfloat16* gb    = (__hip_bfloat16*)(ws + off); off += (size_t)ROWS * ID * 2;  // s / gelu out
  __hip_bfloat16* sb = gb;   // sigmoid out aliases gb (consumed before FFN1 rewrites)

  dim3 tb(32, 8);
  transpose_bf16_kernel<<<dim3(HD/32, HD/32, NL), tb, 0, stream>>>(retW, retWt, HD, HD);
  transpose_bf16_kernel<<<dim3(ID/32, HD/32, NL), tb, 0, stream>>>(W1, W1t, HD, ID);
  transpose_bf16_kernel<<<dim3(HD/32, ID/32, NL), tb, 0, stream>>>(W2, W2t, ID, HD);

  embed_ln_kernel<<<ROWS/4, 256, 0, stream>>>(ids, wemb, pemb, elns, elnb, hb);

  for (int l = 0; l < NL; l++) {
    // s = sigmoid(h @ retW + rb) -> sb (bf16). BN=96 (512 blocks = 2/CU)
    gemm_mfma_kernel<96, 1, 0><<<dim3(ROWS/128, HD/96), 256, 0, stream>>>(
        hb, retWt + (size_t)l * HD * HD, retb + (size_t)l * HD,
        nullptr, sb, ROWS, HD, HD);
    // h1 = LN(h + retention(s))  [fused scan+LN, warm-up 32]
    scan_ln_kernel<<<NB * (SL/32), 768, 0, stream>>>(sb, hb,
        ln1s + (size_t)l * HD, ln1b + (size_t)l * HD, h1b);
    // g = gelu(h1 @ W1 + b1) -> gb (bf16). BN=128 (1536 blocks)
    gemm_mfma_kernel<128, 2, 0><<<dim3(ROWS/128, ID/128), 256, 0, stream>>>(
        h1b, W1t + (size_t)l * ID * HD, b1 + (size_t)l * ID,
        nullptr, gb, ROWS, ID, HD);
    // y = h1 + (g @ W2 + b2) -> yb (bf16). BN=96 (512 blocks = 2/CU)
    gemm_mfma_kernel<96, 0, 1><<<dim3(ROWS/128, HD/96), 256, 0, stream>>>(
        gb, W2t + (size_t)l * HD * ID, b2 + (size_t)l * HD,
        h1b, yb, ROWS, HD, ID);
    if (l < NL - 1) {
      // h = LN(y)
      ln_row_kernel<0><<<ROWS/4, 256, 0, stream>>>(yb,
          ln2s + (size_t)l * HD, ln2b + (size_t)l * HD, hb, nullptr);
    } else {
      // last layer: out = LNf(bf16(LN2(y))) fused — skips hb round-trip
      ln2_final_kernel<<<ROWS/4, 256, 0, stream>>>(yb,
          ln2s + (size_t)l * HD, ln2b + (size_t)l * HD, fins, finb, out);
    }
  }
}

// Round 20
// 541.005 us; speedup vs baseline: 1.1119x; 1.0145x over previous
//
#include <hip/hip_runtime.h>
#include <hip/hip_bf16.h>
#include <cstdint>
#include <cstddef>

// Problem dims
#define HD   768
#define ID   3072
#define NB   4
#define SL   2048
#define NL   4
#define ROWS (NB*SL)   // 8192

typedef __attribute__((ext_vector_type(8))) short bf16x8s;
typedef __attribute__((ext_vector_type(4))) float f32x4;
typedef __attribute__((ext_vector_type(4))) unsigned short u16x4;

typedef __attribute__((address_space(1))) const unsigned int g_as1_u32;
typedef __attribute__((address_space(3))) unsigned int lds_as3_u32;

// async 16B/lane global->LDS copy (wave-uniform LDS base + lane*16)
__device__ __forceinline__ void gl2lds16(__hip_bfloat16* l, const __hip_bfloat16* g) {
  __builtin_amdgcn_global_load_lds((g_as1_u32*)g, (lds_as3_u32*)l, 16, 0, 0);
}

__device__ __forceinline__ float bfu2f(unsigned short u) {
  return __uint_as_float((unsigned int)u << 16);
}
__device__ __forceinline__ unsigned short f2bfu(float f) {
  __hip_bfloat16 h = __float2bfloat16(f);
  return *reinterpret_cast<unsigned short*>(&h);
}

// ---------------------------------------------------------------------------
// Wave-per-row LayerNorm: block=256 (4 waves), wave w does row blockIdx*4+w.
// ---------------------------------------------------------------------------
template <int OUTF32>
__global__ __launch_bounds__(256) void ln_row_kernel(
    const __hip_bfloat16* __restrict__ x,
    const float* __restrict__ scale, const float* __restrict__ bias,
    __hip_bfloat16* __restrict__ ob, float* __restrict__ of)
{
  const int w = threadIdx.x >> 6, lane = threadIdx.x & 63;
  const size_t row = (size_t)blockIdx.x * 4 + w;
  const __hip_bfloat16* xr = x + row * HD;
  float v[12];
#pragma unroll
  for (int c = 0; c < 3; c++) {
    u16x4 u = *reinterpret_cast<const u16x4*>(xr + c * 256 + lane * 4);
#pragma unroll
    for (int i = 0; i < 4; i++) v[c * 4 + i] = bfu2f(u[i]);
  }
  float s = 0.f;
#pragma unroll
  for (int i = 0; i < 12; i++) s += v[i];
#pragma unroll
  for (int m = 1; m < 64; m <<= 1) s += __shfl_xor(s, m);
  float mean = s * (1.0f / 768.0f);
  float q = 0.f;
#pragma unroll
  for (int i = 0; i < 12; i++) { float d = v[i] - mean; q += d * d; }
#pragma unroll
  for (int m = 1; m < 64; m <<= 1) q += __shfl_xor(q, m);
  float rstd = rsqrtf(q * (1.0f / 768.0f) + 1e-5f);
#pragma unroll
  for (int c = 0; c < 3; c++) {
    int j0 = c * 256 + lane * 4;
    if (OUTF32) {
      f32x4 o;
#pragma unroll
      for (int i = 0; i < 4; i++)
        o[i] = (v[c * 4 + i] - mean) * rstd * scale[j0 + i] + bias[j0 + i];
      *reinterpret_cast<f32x4*>(of + row * HD + j0) = o;
    } else {
      u16x4 o;
#pragma unroll
      for (int i = 0; i < 4; i++)
        o[i] = f2bfu((v[c * 4 + i] - mean) * rstd * scale[j0 + i] + bias[j0 + i]);
      *reinterpret_cast<u16x4*>(ob + row * HD + j0) = o;
    }
  }
}

// ---------------------------------------------------------------------------
// Fused LN2 + final LN (last layer only): out = LNf(bf16(LN2(y))).
// ---------------------------------------------------------------------------
__global__ __launch_bounds__(256) void ln2_final_kernel(
    const __hip_bfloat16* __restrict__ y,
    const float* __restrict__ s2, const float* __restrict__ b2,
    const float* __restrict__ fs, const float* __restrict__ fb,
    float* __restrict__ out)
{
  const int w = threadIdx.x >> 6, lane = threadIdx.x & 63;
  const size_t row = (size_t)blockIdx.x * 4 + w;
  const __hip_bfloat16* xr = y + row * HD;
  float v[12];
#pragma unroll
  for (int c = 0; c < 3; c++) {
    u16x4 u = *reinterpret_cast<const u16x4*>(xr + c * 256 + lane * 4);
#pragma unroll
    for (int i = 0; i < 4; i++) v[c * 4 + i] = bfu2f(u[i]);
  }
  float s = 0.f;
#pragma unroll
  for (int i = 0; i < 12; i++) s += v[i];
#pragma unroll
  for (int m = 1; m < 64; m <<= 1) s += __shfl_xor(s, m);
  float mean = s * (1.0f / 768.0f);
  float q = 0.f;
#pragma unroll
  for (int i = 0; i < 12; i++) { float d = v[i] - mean; q += d * d; }
#pragma unroll
  for (int m = 1; m < 64; m <<= 1) q += __shfl_xor(q, m);
  float rstd = rsqrtf(q * (1.0f / 768.0f) + 1e-5f);
  // LN2 result, rounded to bf16 exactly as the unfused path stored it
  float t[12];
#pragma unroll
  for (int c = 0; c < 3; c++) {
    int j0 = c * 256 + lane * 4;
#pragma unroll
    for (int i = 0; i < 4; i++)
      t[c * 4 + i] = bfu2f(f2bfu((v[c * 4 + i] - mean) * rstd * s2[j0 + i] + b2[j0 + i]));
  }
  // final LN over t
  float s2m = 0.f;
#pragma unroll
  for (int i = 0; i < 12; i++) s2m += t[i];
#pragma unroll
  for (int m = 1; m < 64; m <<= 1) s2m += __shfl_xor(s2m, m);
  float mean2 = s2m * (1.0f / 768.0f);
  float q2 = 0.f;
#pragma unroll
  for (int i = 0; i < 12; i++) { float d = t[i] - mean2; q2 += d * d; }
#pragma unroll
  for (int m = 1; m < 64; m <<= 1) q2 += __shfl_xor(q2, m);
  float rstd2 = rsqrtf(q2 * (1.0f / 768.0f) + 1e-5f);
#pragma unroll
  for (int c = 0; c < 3; c++) {
    int j0 = c * 256 + lane * 4;
    f32x4 o;
#pragma unroll
    for (int i = 0; i < 4; i++)
      o[i] = (t[c * 4 + i] - mean2) * rstd2 * fs[j0 + i] + fb[j0 + i];
    *reinterpret_cast<f32x4*>(out + row * HD + j0) = o;
  }
}

// embedding gather + pos add + LN (wave-per-row), writes bf16
__global__ __launch_bounds__(256) void embed_ln_kernel(
    const int* __restrict__ ids, const float* __restrict__ wemb,
    const float* __restrict__ pemb,
    const float* __restrict__ scale, const float* __restrict__ bias,
    __hip_bfloat16* __restrict__ ob)
{
  const int w = threadIdx.x >> 6, lane = threadIdx.x & 63;
  const size_t row = (size_t)blockIdx.x * 4 + w;
  const int t = (int)(row & (SL - 1));
  const int id = ids[row];
  float v[12];
#pragma unroll
  for (int c = 0; c < 3; c++) {
    int j0 = c * 256 + lane * 4;
    f32x4 a = *reinterpret_cast<const f32x4*>(wemb + (size_t)id * HD + j0);
    f32x4 p = *reinterpret_cast<const f32x4*>(pemb + (size_t)t * HD + j0);
#pragma unroll
    for (int i = 0; i < 4; i++) v[c * 4 + i] = a[i] + p[i];
  }
  float s = 0.f;
#pragma unroll
  for (int i = 0; i < 12; i++) s += v[i];
#pragma unroll
  for (int m = 1; m < 64; m <<= 1) s += __shfl_xor(s, m);
  float mean = s * (1.0f / 768.0f);
  float q = 0.f;
#pragma unroll
  for (int i = 0; i < 12; i++) { float d = v[i] - mean; q += d * d; }
#pragma unroll
  for (int m = 1; m < 64; m <<= 1) q += __shfl_xor(q, m);
  float rstd = rsqrtf(q * (1.0f / 768.0f) + 1e-5f);
#pragma unroll
  for (int c = 0; c < 3; c++) {
    int j0 = c * 256 + lane * 4;
    u16x4 o;
#pragma unroll
    for (int i = 0; i < 4; i++)
      o[i] = f2bfu((v[c * 4 + i] - mean) * rstd * scale[j0 + i] + bias[j0 + i]);
    *reinterpret_cast<u16x4*>(ob + row * HD + j0) = o;
  }
}

// ---------------------------------------------------------------------------
// Merged weight transpose + f32->bf16 for retW, W1, W2 (single launch).
// Tile 32x32, tb (32,8). Linear block id -> {weight, layer, n-tile, k-tile}.
//   retW: 4 layers x 24x24 tiles = 2304
//   W1:   4 layers x 96(n) x 24(k) = 9216
//   W2:   4 layers x 24(n) x 96(k) = 9216      total 20736 blocks
// ---------------------------------------------------------------------------
__global__ __launch_bounds__(256) void transpose_all_kernel(
    const float* __restrict__ retW, const float* __restrict__ W1,
    const float* __restrict__ W2,
    __hip_bfloat16* __restrict__ retWt, __hip_bfloat16* __restrict__ W1t,
    __hip_bfloat16* __restrict__ W2t)
{
  __shared__ float tile[32][33];
  int id = blockIdx.x;
  const float* in; __hip_bfloat16* outp; int K, N, n0, k0;
  if (id < 2304) {                          // retW [l][K=HD][N=HD]
    int l = id / 576, rem = id % 576;
    K = HD; N = HD;
    n0 = (rem % 24) * 32; k0 = (rem / 24) * 32;
    in = retW + (size_t)l * HD * HD; outp = retWt + (size_t)l * HD * HD;
  } else if (id < 2304 + 9216) {            // W1 [l][K=HD][N=ID]
    int id2 = id - 2304;
    int l = id2 / 2304, rem = id2 % 2304;
    K = HD; N = ID;
    n0 = (rem % 96) * 32; k0 = (rem / 96) * 32;
    in = W1 + (size_t)l * HD * ID; outp = W1t + (size_t)l * HD * ID;
  } else {                                  // W2 [l][K=ID][N=HD]
    int id2 = id - 2304 - 9216;
    int l = id2 / 2304, rem = id2 % 2304;
    K = ID; N = HD;
    n0 = (rem % 24) * 32; k0 = (rem / 24) * 32;
    in = W2 + (size_t)l * ID * HD; outp = W2t + (size_t)l * ID * HD;
  }
  int tx = threadIdx.x, ty = threadIdx.y;   // (32, 8)
#pragma unroll
  for (int i = 0; i < 4; i++)
    tile[ty + i * 8][tx] = in[(size_t)(k0 + ty + i * 8) * N + n0 + tx];
  __syncthreads();
#pragma unroll
  for (int i = 0; i < 4; i++)
    outp[(size_t)(n0 + ty + i * 8) * K + k0 + tx] = __float2bfloat16(tile[tx][ty + i * 8]);
}

// ---------------------------------------------------------------------------
// Fused retention scan + residual + LN1.
// Block (b, chunk of 32 timesteps), 768 threads (12 waves), 1 column/thread.
// Phase 1: 16-step warm-up (0.5^16 ~ 1.5e-5, far below bf16 rounding of z) +
// 32 steps z = h + r -> LDS. Phase 2: wave-per-row LN -> h1 (bf16).
// ---------------------------------------------------------------------------
__global__ __launch_bounds__(768) void scan_ln_kernel(
    const __hip_bfloat16* __restrict__ s,
    const __hip_bfloat16* __restrict__ h,
    const float* __restrict__ scale, const float* __restrict__ bias,
    __hip_bfloat16* __restrict__ h1)
{
  __shared__ __hip_bfloat16 zt[32][HD];     // 48 KB
  const int col = threadIdx.x;              // 0..767
  const int nchunk = SL / 32;               // 64
  const int c = blockIdx.x & (nchunk - 1);
  const int b = blockIdx.x / nchunk;
  const int tstart = c * 32;
  int t0 = tstart - 16; if (t0 < 0) t0 = 0;
  const __hip_bfloat16* sp = s + (size_t)b * SL * HD + col;
  const __hip_bfloat16* hp = h + (size_t)b * SL * HD + col;
  float acc = 0.f;
#pragma unroll 8
  for (int t = t0; t < tstart; ++t)
    acc = 0.5f * (__bfloat162float(sp[(size_t)t * HD]) + acc);
#pragma unroll 8
  for (int tt = 0; tt < 32; ++tt) {
    int t = tstart + tt;
    acc = 0.5f * (__bfloat162float(sp[(size_t)t * HD]) + acc);
    zt[tt][col] = __float2bfloat16(acc + __bfloat162float(hp[(size_t)t * HD]));
  }
  __syncthreads();
  // LN phase: 12 waves, wave wv handles rows wv, wv+12, wv+24 (<32)
  const int wv = threadIdx.x >> 6, lane = threadIdx.x & 63;
  for (int row = wv; row < 32; row += 12) {
    float v[12];
#pragma unroll
    for (int cc = 0; cc < 3; cc++) {
      u16x4 u = *reinterpret_cast<const u16x4*>(&zt[row][cc * 256 + lane * 4]);
#pragma unroll
      for (int i = 0; i < 4; i++) v[cc * 4 + i] = bfu2f(u[i]);
    }
    float sm = 0.f;
#pragma unroll
    for (int i = 0; i < 12; i++) sm += v[i];
#pragma unroll
    for (int m = 1; m < 64; m <<= 1) sm += __shfl_xor(sm, m);
    float mean = sm * (1.0f / 768.0f);
    float q = 0.f;
#pragma unroll
    for (int i = 0; i < 12; i++) { float d = v[i] - mean; q += d * d; }
#pragma unroll
    for (int m = 1; m < 64; m <<= 1) q += __shfl_xor(q, m);
    float rstd = rsqrtf(q * (1.0f / 768.0f) + 1e-5f);
    __hip_bfloat16* orow = h1 + ((size_t)b * SL + tstart + row) * HD;
#pragma unroll
    for (int cc = 0; cc < 3; cc++) {
      int j0 = cc * 256 + lane * 4;
      u16x4 o;
#pragma unroll
      for (int i = 0; i < 4; i++)
        o[i] = f2bfu((v[cc * 4 + i] - mean) * rstd * scale[j0 + i] + bias[j0 + i]);
      *reinterpret_cast<u16x4*>(orow + j0) = o;
    }
  }
}

// ---------------------------------------------------------------------------
// Counted-vmcnt pipelined MFMA GEMM (r12 schedule) + coalesced LDS epilogue.
// BM=128, 4 waves (256 thr), BK=64, 2 LDS buffers, 2 blocks/CU.
// ---------------------------------------------------------------------------
template <int BN, int ACT, int RADD>
__global__ __launch_bounds__(256, 2) void gemm_mfma_kernel(
    const __hip_bfloat16* __restrict__ A,
    const __hip_bfloat16* __restrict__ Bt,
    const float* __restrict__ bias,
    const __hip_bfloat16* __restrict__ R,
    __hip_bfloat16* __restrict__ Cb,
    int M, int N, int K)
{
  constexpr int NF = BN / 32;               // N-frags per wave: 4 or 3
  constexpr int ABUF = 128 * 64;            // A buffer elems (16KB)
  constexpr int BBUF = BN * 64;             // B buffer elems (16/12KB)
  constexpr int CP = BN + 8;                // padded C-tile stride (elems)
  static_assert(128 * CP <= 2 * ABUF + 2 * BBUF, "C tile must fit in smem");
  __shared__ __align__(16) __hip_bfloat16 smem[2 * ABUF + 2 * BBUF];
  __hip_bfloat16* As = smem;
  __hip_bfloat16* Bs = smem + 2 * ABUF;
  const int m0 = blockIdx.x * 128;
  const int n0 = blockIdx.y * BN;
  const int tid  = threadIdx.x;
  const int lane = tid & 63;
  const int w    = tid >> 6;                // wave 0..3
  const int wr   = w >> 1;                  // 0..1 (M half, 64 rows)
  const int wc   = w & 1;                   // 0..1 (N half)
  const int lr   = lane & 15;
  const int kg   = lane >> 4;               // 0..3

  f32x4 acc[4][NF];
#pragma unroll
  for (int i = 0; i < 4; i++)
#pragma unroll
    for (int j = 0; j < NF; j++) acc[i][j] = (f32x4){0.f, 0.f, 0.f, 0.f};

  // staging: pass = 256 thr x 16B = 32 rows x 128B. Wave w rows w*8..w*8+7.
  // lane l: row w*8 + l/8, LDS slot l%8, global k-slot (l%8)^(l/8).
  const int prow = lane >> 3;               // 0..7
  const int pslot = lane & 7;
  const int gslot = pslot ^ prow;
  const __hip_bfloat16* aS = A  + (size_t)(m0 + w * 8 + prow) * K + gslot * 8;
  const __hip_bfloat16* bS = Bt + (size_t)(n0 + w * 8 + prow) * K + gslot * 8;
  const size_t K32g = (size_t)32 * K;       // 32-row pass stride (global)
  const int ldsw = w << 9;                  // w*512 elems (8 rows x 64)

  // per-wave loads per stage: A 4 passes + B NF passes = 8 (BN=128) / 7 (96)
  auto stage = [&](int buf, int k0) {
    __hip_bfloat16* Ab = As + buf * ABUF + ldsw;
    __hip_bfloat16* Bb = Bs + buf * BBUF + ldsw;
    gl2lds16(Ab,         aS + k0);               // A rows 0-31
    gl2lds16(Ab + 2048,  aS + k0 + K32g);        // A rows 32-63
    gl2lds16(Ab + 4096,  aS + k0 + 2 * K32g);    // A rows 64-95
    gl2lds16(Ab + 6144,  aS + k0 + 3 * K32g);    // A rows 96-127
    gl2lds16(Bb,         bS + k0);               // B rows 0-31
    gl2lds16(Bb + 2048,  bS + k0 + K32g);        // B rows 32-63
    gl2lds16(Bb + 4096,  bS + k0 + 2 * K32g);    // B rows 64-95
    if constexpr (BN == 128)
      gl2lds16(Bb + 6144, bS + k0 + 3 * K32g);   // B rows 96-127
  };

  // read-side swizzled slots (per-lane constants)
  const int rx = lr & 7;
  const int arow = wr * 64 + lr;            // + i*16
  const int brow = wc * (BN / 2) + lr;      // + j*16

  const int nt = K >> 6;                    // BK=64 tiles (12 or 48)
  stage(0, 0);
  stage(1, 64);

  for (int t = 0; t < nt; ++t) {
    const int cur = t & 1;
    // counted wait: tile t's own loads done; tile t+1's stay in flight
    if (t == nt - 1) {
      asm volatile("s_waitcnt vmcnt(0)" ::: "memory");
    } else {
      if constexpr (BN == 128) asm volatile("s_waitcnt vmcnt(8)" ::: "memory");
      else                     asm volatile("s_waitcnt vmcnt(7)" ::: "memory");
    }
    asm volatile("s_barrier" ::: "memory");          // all waves: tile t ready

    const __hip_bfloat16* Ab = As + cur * ABUF;
    const __hip_bfloat16* Bb = Bs + cur * BBUF;
    bf16x8s af[2][4], bq[2][NF];
#pragma unroll
    for (int kk = 0; kk < 2; kk++) {
      const int sl = ((kk * 4 + kg) ^ rx) * 8;
#pragma unroll
      for (int i = 0; i < 4; i++)
        af[kk][i] = *reinterpret_cast<const bf16x8s*>(&Ab[(arow + i * 16) * 64 + sl]);
#pragma unroll
      for (int j = 0; j < NF; j++)
        bq[kk][j] = *reinterpret_cast<const bf16x8s*>(&Bb[(brow + j * 16) * 64 + sl]);
    }
    asm volatile("s_waitcnt lgkmcnt(0)" ::: "memory");  // frags in regs
    asm volatile("s_barrier" ::: "memory");             // all waves done reading

    if (t + 2 < nt) stage(cur, (t + 2) << 6);  // overwrite just-read buffer

#pragma unroll
    for (int kk = 0; kk < 2; kk++)
#pragma unroll
      for (int i = 0; i < 4; i++)
#pragma unroll
        for (int j = 0; j < NF; j++)
          acc[i][j] = __builtin_amdgcn_mfma_f32_16x16x32_bf16(
              af[kk][i], bq[kk][j], acc[i][j], 0, 0, 0);
  }

  // ---- epilogue: dump activated tile to LDS, then coalesced write-out ----
  __hip_bfloat16* Ct = smem;
#pragma unroll
  for (int i = 0; i < 4; i++)
#pragma unroll
    for (int j = 0; j < NF; j++) {
      int cl = wc * (BN / 2) + j * 16 + lr;      // col within tile
      float bv = bias[n0 + cl];
#pragma unroll
      for (int r = 0; r < 4; r++) {
        int rl = wr * 64 + i * 16 + kg * 4 + r;  // row within tile
        float v = acc[i][j][r] + bv;
        if (ACT == 1) v = 1.f / (1.f + __expf(-v));
        else if (ACT == 2) {
          float x = v;
          float z = 1.5957691216057308f * (x + 0.044715f * x * x * x);
          v = x / (1.f + __expf(-z));
        }
        if (RADD) v += __bfloat162float(R[(size_t)(m0 + rl) * N + n0 + cl]);
        Ct[rl * CP + cl] = __float2bfloat16(v);
      }
    }
  __syncthreads();

  // coalesced write-out: 16B chunks, 16 consecutive lanes = 256B runs
  constexpr int CPR = BN / 8;               // 16B chunks per row (16 or 12)
  constexpr int NPASS = 128 * CPR / 256;    // 8 or 6 passes
#pragma unroll
  for (int p = 0; p < NPASS; ++p) {
    int idx = p * 256 + tid;
    int row = idx / CPR;
    int ch  = idx - row * CPR;
    uint4 d = *reinterpret_cast<const uint4*>(&Ct[row * CP + ch * 8]);
    *reinterpret_cast<uint4*>(&Cb[(size_t)(m0 + row) * N + n0 + ch * 8]) = d;
  }
}

// ---------------------------------------------------------------------------
extern "C" void kernel_launch(void* const* d_in, const int* in_sizes, int n_in,
                              void* d_out, int out_size, void* d_ws, size_t ws_size,
                              hipStream_t stream)
{
  const int*   ids  = (const int*)d_in[0];
  const float* wemb = (const float*)d_in[1];
  const float* pemb = (const float*)d_in[2];
  const float* elns = (const float*)d_in[3];
  const float* elnb = (const float*)d_in[4];
  const float* retW = (const float*)d_in[5];
  const float* retb = (const float*)d_in[6];
  const float* ln1s = (const float*)d_in[7];
  const float* ln1b = (const float*)d_in[8];
  const float* W1   = (const float*)d_in[9];
  const float* b1   = (const float*)d_in[10];
  const float* W2   = (const float*)d_in[11];
  const float* b2   = (const float*)d_in[12];
  const float* ln2s = (const float*)d_in[13];
  const float* ln2b = (const float*)d_in[14];
  const float* fins = (const float*)d_in[15];
  const float* finb = (const float*)d_in[16];
  float* out = (float*)d_out;

  char* ws = (char*)d_ws;
  size_t off = 0;
  __hip_bfloat16* retWt = (__hip_bfloat16*)(ws + off); off += (size_t)NL * HD * HD * 2;
  __hip_bfloat16* W1t   = (__hip_bfloat16*)(ws + off); off += (size_t)NL * HD * ID * 2;
  __hip_bfloat16* W2t   = (__hip_bfloat16*)(ws + off); off += (size_t)NL * ID * HD * 2;
  __hip_bfloat16* hb    = (__hip_bfloat16*)(ws + off); off += (size_t)ROWS * HD * 2;  // residual h
  __hip_bfloat16* h1b   = (__hip_bfloat16*)(ws + off); off += (size_t)ROWS * HD * 2;  // h1
  __hip_bfloat16* yb    = (__hip_bfloat16*)(ws + off); off += (size_t)ROWS * HD * 2;  // h1+ffn2
  __hip_bfloat16* gb    = (__hip_bfloat16*)(ws + off); off += (size_t)ROWS * ID * 2;  // s / gelu out
  __hip_bfloat16* sb = gb;   // sigmoid out aliases gb (consumed before FFN1 rewrites)

  // all three weight transposes in one launch (20736 tiles)
  transpose_all_kernel<<<dim3(20736), dim3(32, 8), 0, stream>>>(
      retW, W1, W2, retWt, W1t, W2t);

  embed_ln_kernel<<<ROWS/4, 256, 0, stream>>>(ids, wemb, pemb, elns, elnb, hb);

  for (int l = 0; l < NL; l++) {
    // s = sigmoid(h @ retW + rb) -> sb (bf16). BN=96 (512 blocks = 2/CU)
    gemm_mfma_kernel<96, 1, 0><<<dim3(ROWS/128, HD/96), 256, 0, stream>>>(
        hb, retWt + (size_t)l * HD * HD, retb + (size_t)l * HD,
        nullptr, sb, ROWS, HD, HD);
    // h1 = LN(h + retention(s))  [fused scan+LN, warm-up 16]
    scan_ln_kernel<<<NB * (SL/32), 768, 0, stream>>>(sb, hb,
        ln1s + (size_t)l * HD, ln1b + (size_t)l * HD, h1b);
    // g = gelu(h1 @ W1 + b1) -> gb (bf16). BN=128 (1536 blocks)
    gemm_mfma_kernel<128, 2, 0><<<dim3(ROWS/128, ID/128), 256, 0, stream>>>(
        h1b, W1t + (size_t)l * ID * HD, b1 + (size_t)l * ID,
        nullptr, gb, ROWS, ID, HD);
    // y = h1 + (g @ W2 + b2) -> yb (bf16). BN=96 (512 blocks = 2/CU)
    gemm_mfma_kernel<96, 0, 1><<<dim3(ROWS/128, HD/96), 256, 0, stream>>>(
        gb, W2t + (size_t)l * HD * ID, b2 + (size_t)l * HD,
        h1b, yb, ROWS, HD, ID);
    if (l < NL - 1) {
      // h = LN(y)
      ln_row_kernel<0><<<ROWS/4, 256, 0, stream>>>(yb,
          ln2s + (size_t)l * HD, ln2b + (size_t)l * HD, hb, nullptr);
    } else {
      // last layer: out = LNf(bf16(LN2(y))) fused — skips hb round-trip
      ln2_final_kernel<<<ROWS/4, 256, 0, stream>>>(yb,
          ln2s + (size_t)l * HD, ln2b + (size_t)l * HD, fins, finb, out);
    }
  }
}

// Round 21
// 532.453 us; speedup vs baseline: 1.1297x; 1.0161x over previous
//
#include <hip/hip_runtime.h>
#include <hip/hip_bf16.h>
#include <cstdint>
#include <cstddef>

// Problem dims
#define HD   768
#define ID   3072
#define NB   4
#define SL   2048
#define NL   4
#define ROWS (NB*SL)   // 8192

typedef __attribute__((ext_vector_type(8))) short bf16x8s;
typedef __attribute__((ext_vector_type(4))) float f32x4;
typedef __attribute__((ext_vector_type(4))) unsigned short u16x4;

typedef __attribute__((address_space(1))) const unsigned int g_as1_u32;
typedef __attribute__((address_space(3))) unsigned int lds_as3_u32;

// async 16B/lane global->LDS copy (wave-uniform LDS base + lane*16)
__device__ __forceinline__ void gl2lds16(__hip_bfloat16* l, const __hip_bfloat16* g) {
  __builtin_amdgcn_global_load_lds((g_as1_u32*)g, (lds_as3_u32*)l, 16, 0, 0);
}

__device__ __forceinline__ float bfu2f(unsigned short u) {
  return __uint_as_float((unsigned int)u << 16);
}
__device__ __forceinline__ unsigned short f2bfu(float f) {
  __hip_bfloat16 h = __float2bfloat16(f);
  return *reinterpret_cast<unsigned short*>(&h);
}

// ---------------------------------------------------------------------------
// Wave-per-row LayerNorm: block=256 (4 waves), wave w does row blockIdx*4+w.
// ---------------------------------------------------------------------------
template <int OUTF32>
__global__ __launch_bounds__(256) void ln_row_kernel(
    const __hip_bfloat16* __restrict__ x,
    const float* __restrict__ scale, const float* __restrict__ bias,
    __hip_bfloat16* __restrict__ ob, float* __restrict__ of)
{
  const int w = threadIdx.x >> 6, lane = threadIdx.x & 63;
  const size_t row = (size_t)blockIdx.x * 4 + w;
  const __hip_bfloat16* xr = x + row * HD;
  float v[12];
#pragma unroll
  for (int c = 0; c < 3; c++) {
    u16x4 u = *reinterpret_cast<const u16x4*>(xr + c * 256 + lane * 4);
#pragma unroll
    for (int i = 0; i < 4; i++) v[c * 4 + i] = bfu2f(u[i]);
  }
  float s = 0.f;
#pragma unroll
  for (int i = 0; i < 12; i++) s += v[i];
#pragma unroll
  for (int m = 1; m < 64; m <<= 1) s += __shfl_xor(s, m);
  float mean = s * (1.0f / 768.0f);
  float q = 0.f;
#pragma unroll
  for (int i = 0; i < 12; i++) { float d = v[i] - mean; q += d * d; }
#pragma unroll
  for (int m = 1; m < 64; m <<= 1) q += __shfl_xor(q, m);
  float rstd = rsqrtf(q * (1.0f / 768.0f) + 1e-5f);
#pragma unroll
  for (int c = 0; c < 3; c++) {
    int j0 = c * 256 + lane * 4;
    if (OUTF32) {
      f32x4 o;
#pragma unroll
      for (int i = 0; i < 4; i++)
        o[i] = (v[c * 4 + i] - mean) * rstd * scale[j0 + i] + bias[j0 + i];
      *reinterpret_cast<f32x4*>(of + row * HD + j0) = o;
    } else {
      u16x4 o;
#pragma unroll
      for (int i = 0; i < 4; i++)
        o[i] = f2bfu((v[c * 4 + i] - mean) * rstd * scale[j0 + i] + bias[j0 + i]);
      *reinterpret_cast<u16x4*>(ob + row * HD + j0) = o;
    }
  }
}

// ---------------------------------------------------------------------------
// Fused LN2 + final LN (last layer only): out = LNf(bf16(LN2(y))).
// ---------------------------------------------------------------------------
__global__ __launch_bounds__(256) void ln2_final_kernel(
    const __hip_bfloat16* __restrict__ y,
    const float* __restrict__ s2, const float* __restrict__ b2,
    const float* __restrict__ fs, const float* __restrict__ fb,
    float* __restrict__ out)
{
  const int w = threadIdx.x >> 6, lane = threadIdx.x & 63;
  const size_t row = (size_t)blockIdx.x * 4 + w;
  const __hip_bfloat16* xr = y + row * HD;
  float v[12];
#pragma unroll
  for (int c = 0; c < 3; c++) {
    u16x4 u = *reinterpret_cast<const u16x4*>(xr + c * 256 + lane * 4);
#pragma unroll
    for (int i = 0; i < 4; i++) v[c * 4 + i] = bfu2f(u[i]);
  }
  float s = 0.f;
#pragma unroll
  for (int i = 0; i < 12; i++) s += v[i];
#pragma unroll
  for (int m = 1; m < 64; m <<= 1) s += __shfl_xor(s, m);
  float mean = s * (1.0f / 768.0f);
  float q = 0.f;
#pragma unroll
  for (int i = 0; i < 12; i++) { float d = v[i] - mean; q += d * d; }
#pragma unroll
  for (int m = 1; m < 64; m <<= 1) q += __shfl_xor(q, m);
  float rstd = rsqrtf(q * (1.0f / 768.0f) + 1e-5f);
  // LN2 result, rounded to bf16 exactly as the unfused path stored it
  float t[12];
#pragma unroll
  for (int c = 0; c < 3; c++) {
    int j0 = c * 256 + lane * 4;
#pragma unroll
    for (int i = 0; i < 4; i++)
      t[c * 4 + i] = bfu2f(f2bfu((v[c * 4 + i] - mean) * rstd * s2[j0 + i] + b2[j0 + i]));
  }
  // final LN over t
  float s2m = 0.f;
#pragma unroll
  for (int i = 0; i < 12; i++) s2m += t[i];
#pragma unroll
  for (int m = 1; m < 64; m <<= 1) s2m += __shfl_xor(s2m, m);
  float mean2 = s2m * (1.0f / 768.0f);
  float q2 = 0.f;
#pragma unroll
  for (int i = 0; i < 12; i++) { float d = t[i] - mean2; q2 += d * d; }
#pragma unroll
  for (int m = 1; m < 64; m <<= 1) q2 += __shfl_xor(q2, m);
  float rstd2 = rsqrtf(q2 * (1.0f / 768.0f) + 1e-5f);
#pragma unroll
  for (int c = 0; c < 3; c++) {
    int j0 = c * 256 + lane * 4;
    f32x4 o;
#pragma unroll
    for (int i = 0; i < 4; i++)
      o[i] = (t[c * 4 + i] - mean2) * rstd2 * fs[j0 + i] + fb[j0 + i];
    *reinterpret_cast<f32x4*>(out + row * HD + j0) = o;
  }
}

// embedding gather + pos add + LN (wave-per-row), writes bf16
__global__ __launch_bounds__(256) void embed_ln_kernel(
    const int* __restrict__ ids, const float* __restrict__ wemb,
    const float* __restrict__ pemb,
    const float* __restrict__ scale, const float* __restrict__ bias,
    __hip_bfloat16* __restrict__ ob)
{
  const int w = threadIdx.x >> 6, lane = threadIdx.x & 63;
  const size_t row = (size_t)blockIdx.x * 4 + w;
  const int t = (int)(row & (SL - 1));
  const int id = ids[row];
  float v[12];
#pragma unroll
  for (int c = 0; c < 3; c++) {
    int j0 = c * 256 + lane * 4;
    f32x4 a = *reinterpret_cast<const f32x4*>(wemb + (size_t)id * HD + j0);
    f32x4 p = *reinterpret_cast<const f32x4*>(pemb + (size_t)t * HD + j0);
#pragma unroll
    for (int i = 0; i < 4; i++) v[c * 4 + i] = a[i] + p[i];
  }
  float s = 0.f;
#pragma unroll
  for (int i = 0; i < 12; i++) s += v[i];
#pragma unroll
  for (int m = 1; m < 64; m <<= 1) s += __shfl_xor(s, m);
  float mean = s * (1.0f / 768.0f);
  float q = 0.f;
#pragma unroll
  for (int i = 0; i < 12; i++) { float d = v[i] - mean; q += d * d; }
#pragma unroll
  for (int m = 1; m < 64; m <<= 1) q += __shfl_xor(q, m);
  float rstd = rsqrtf(q * (1.0f / 768.0f) + 1e-5f);
#pragma unroll
  for (int c = 0; c < 3; c++) {
    int j0 = c * 256 + lane * 4;
    u16x4 o;
#pragma unroll
    for (int i = 0; i < 4; i++)
      o[i] = f2bfu((v[c * 4 + i] - mean) * rstd * scale[j0 + i] + bias[j0 + i]);
    *reinterpret_cast<u16x4*>(ob + row * HD + j0) = o;
  }
}

// ---------------------------------------------------------------------------
// Merged weight transpose + f32->bf16 for retW, W1, W2 (single launch).
// ---------------------------------------------------------------------------
__global__ __launch_bounds__(256) void transpose_all_kernel(
    const float* __restrict__ retW, const float* __restrict__ W1,
    const float* __restrict__ W2,
    __hip_bfloat16* __restrict__ retWt, __hip_bfloat16* __restrict__ W1t,
    __hip_bfloat16* __restrict__ W2t)
{
  __shared__ float tile[32][33];
  int id = blockIdx.x;
  const float* in; __hip_bfloat16* outp; int K, N, n0, k0;
  if (id < 2304) {                          // retW [l][K=HD][N=HD]
    int l = id / 576, rem = id % 576;
    K = HD; N = HD;
    n0 = (rem % 24) * 32; k0 = (rem / 24) * 32;
    in = retW + (size_t)l * HD * HD; outp = retWt + (size_t)l * HD * HD;
  } else if (id < 2304 + 9216) {            // W1 [l][K=HD][N=ID]
    int id2 = id - 2304;
    int l = id2 / 2304, rem = id2 % 2304;
    K = HD; N = ID;
    n0 = (rem % 96) * 32; k0 = (rem / 96) * 32;
    in = W1 + (size_t)l * HD * ID; outp = W1t + (size_t)l * HD * ID;
  } else {                                  // W2 [l][K=ID][N=HD]
    int id2 = id - 2304 - 9216;
    int l = id2 / 2304, rem = id2 % 2304;
    K = ID; N = HD;
    n0 = (rem % 24) * 32; k0 = (rem / 24) * 32;
    in = W2 + (size_t)l * ID * HD; outp = W2t + (size_t)l * ID * HD;
  }
  int tx = threadIdx.x, ty = threadIdx.y;   // (32, 8)
#pragma unroll
  for (int i = 0; i < 4; i++)
    tile[ty + i * 8][tx] = in[(size_t)(k0 + ty + i * 8) * N + n0 + tx];
  __syncthreads();
#pragma unroll
  for (int i = 0; i < 4; i++)
    outp[(size_t)(n0 + ty + i * 8) * K + k0 + tx] = __float2bfloat16(tile[tx][ty + i * 8]);
}

// ---------------------------------------------------------------------------
// Fused retention scan + residual + LN1 (warm-up 16: 0.5^16 ~ 1.5e-5).
// ---------------------------------------------------------------------------
__global__ __launch_bounds__(768) void scan_ln_kernel(
    const __hip_bfloat16* __restrict__ s,
    const __hip_bfloat16* __restrict__ h,
    const float* __restrict__ scale, const float* __restrict__ bias,
    __hip_bfloat16* __restrict__ h1)
{
  __shared__ __hip_bfloat16 zt[32][HD];     // 48 KB
  const int col = threadIdx.x;              // 0..767
  const int nchunk = SL / 32;               // 64
  const int c = blockIdx.x & (nchunk - 1);
  const int b = blockIdx.x / nchunk;
  const int tstart = c * 32;
  int t0 = tstart - 16; if (t0 < 0) t0 = 0;
  const __hip_bfloat16* sp = s + (size_t)b * SL * HD + col;
  const __hip_bfloat16* hp = h + (size_t)b * SL * HD + col;
  float acc = 0.f;
#pragma unroll 8
  for (int t = t0; t < tstart; ++t)
    acc = 0.5f * (__bfloat162float(sp[(size_t)t * HD]) + acc);
#pragma unroll 8
  for (int tt = 0; tt < 32; ++tt) {
    int t = tstart + tt;
    acc = 0.5f * (__bfloat162float(sp[(size_t)t * HD]) + acc);
    zt[tt][col] = __float2bfloat16(acc + __bfloat162float(hp[(size_t)t * HD]));
  }
  __syncthreads();
  // LN phase: 12 waves, wave wv handles rows wv, wv+12, wv+24 (<32)
  const int wv = threadIdx.x >> 6, lane = threadIdx.x & 63;
  for (int row = wv; row < 32; row += 12) {
    float v[12];
#pragma unroll
    for (int cc = 0; cc < 3; cc++) {
      u16x4 u = *reinterpret_cast<const u16x4*>(&zt[row][cc * 256 + lane * 4]);
#pragma unroll
      for (int i = 0; i < 4; i++) v[cc * 4 + i] = bfu2f(u[i]);
    }
    float sm = 0.f;
#pragma unroll
    for (int i = 0; i < 12; i++) sm += v[i];
#pragma unroll
    for (int m = 1; m < 64; m <<= 1) sm += __shfl_xor(sm, m);
    float mean = sm * (1.0f / 768.0f);
    float q = 0.f;
#pragma unroll
    for (int i = 0; i < 12; i++) { float d = v[i] - mean; q += d * d; }
#pragma unroll
    for (int m = 1; m < 64; m <<= 1) q += __shfl_xor(q, m);
    float rstd = rsqrtf(q * (1.0f / 768.0f) + 1e-5f);
    __hip_bfloat16* orow = h1 + ((size_t)b * SL + tstart + row) * HD;
#pragma unroll
    for (int cc = 0; cc < 3; cc++) {
      int j0 = cc * 256 + lane * 4;
      u16x4 o;
#pragma unroll
      for (int i = 0; i < 4; i++)
        o[i] = f2bfu((v[cc * 4 + i] - mean) * rstd * scale[j0 + i] + bias[j0 + i]);
      *reinterpret_cast<u16x4*>(orow + j0) = o;
    }
  }
}

// ---------------------------------------------------------------------------
// Counted-vmcnt pipelined MFMA GEMM (r12 schedule) + coalesced LDS epilogue.
// BM=128, 4 waves (256 thr), BK=64, 2 LDS buffers, 2 blocks/CU.
// BN in {96,128,192}; per-wave N sub-tile = BN/2 (NF = BN/32 frags).
// ---------------------------------------------------------------------------
template <int BN, int ACT, int RADD>
__global__ __launch_bounds__(256, 2) void gemm_mfma_kernel(
    const __hip_bfloat16* __restrict__ A,
    const __hip_bfloat16* __restrict__ Bt,
    const float* __restrict__ bias,
    const __hip_bfloat16* __restrict__ R,
    __hip_bfloat16* __restrict__ Cb,
    int M, int N, int K)
{
  constexpr int NF = BN / 32;               // N-frags per wave: 3,4,6
  constexpr int BPASS = BN / 32;            // B staging passes (32 rows each)
  constexpr int ABUF = 128 * 64;            // A buffer elems (16KB)
  constexpr int BBUF = BN * 64;             // B buffer elems (12/16/24KB)
  constexpr int CP = BN + 8;                // padded C-tile stride (elems)
  static_assert(128 * CP <= 2 * ABUF + 2 * BBUF, "C tile must fit in smem");
  __shared__ __align__(16) __hip_bfloat16 smem[2 * ABUF + 2 * BBUF];
  __hip_bfloat16* As = smem;
  __hip_bfloat16* Bs = smem + 2 * ABUF;
  const int m0 = blockIdx.x * 128;
  const int n0 = blockIdx.y * BN;
  const int tid  = threadIdx.x;
  const int lane = tid & 63;
  const int w    = tid >> 6;                // wave 0..3
  const int wr   = w >> 1;                  // 0..1 (M half, 64 rows)
  const int wc   = w & 1;                   // 0..1 (N half)
  const int lr   = lane & 15;
  const int kg   = lane >> 4;               // 0..3

  f32x4 acc[4][NF];
#pragma unroll
  for (int i = 0; i < 4; i++)
#pragma unroll
    for (int j = 0; j < NF; j++) acc[i][j] = (f32x4){0.f, 0.f, 0.f, 0.f};

  // staging: pass = 256 thr x 16B = 32 rows x 128B. Wave w rows w*8..w*8+7.
  // lane l: row w*8 + l/8, LDS slot l%8, global k-slot (l%8)^(l/8).
  const int prow = lane >> 3;               // 0..7
  const int pslot = lane & 7;
  const int gslot = pslot ^ prow;
  const __hip_bfloat16* aS = A  + (size_t)(m0 + w * 8 + prow) * K + gslot * 8;
  const __hip_bfloat16* bS = Bt + (size_t)(n0 + w * 8 + prow) * K + gslot * 8;
  const size_t K32g = (size_t)32 * K;       // 32-row pass stride (global)
  const int ldsw = w << 9;                  // w*512 elems (8 rows x 64)

  // per-wave loads per stage: 4 (A) + BPASS (B)
  auto stage = [&](int buf, int k0) {
    __hip_bfloat16* Ab = As + buf * ABUF + ldsw;
    __hip_bfloat16* Bb = Bs + buf * BBUF + ldsw;
#pragma unroll
    for (int p = 0; p < 4; p++)
      gl2lds16(Ab + p * 2048, aS + k0 + p * K32g);
#pragma unroll
    for (int p = 0; p < BPASS; p++)
      gl2lds16(Bb + p * 2048, bS + k0 + p * K32g);
  };

  // read-side swizzled slots (per-lane constants)
  const int rx = lr & 7;
  const int arow = wr * 64 + lr;            // + i*16
  const int brow = wc * (BN / 2) + lr;      // + j*16

  const int nt = K >> 6;                    // BK=64 tiles (12 or 48)
  stage(0, 0);
  stage(1, 64);

  for (int t = 0; t < nt; ++t) {
    const int cur = t & 1;
    // counted wait: tile t's own loads done (= 4+BPASS of t+1 in flight)
    if (t == nt - 1) {
      asm volatile("s_waitcnt vmcnt(0)" ::: "memory");
    } else {
      if constexpr (BN == 192)      asm volatile("s_waitcnt vmcnt(10)" ::: "memory");
      else if constexpr (BN == 128) asm volatile("s_waitcnt vmcnt(8)" ::: "memory");
      else                          asm volatile("s_waitcnt vmcnt(7)" ::: "memory");
    }
    asm volatile("s_barrier" ::: "memory");          // all waves: tile t ready

    const __hip_bfloat16* Ab = As + cur * ABUF;
    const __hip_bfloat16* Bb = Bs + cur * BBUF;
    bf16x8s af[2][4], bq[2][NF];
#pragma unroll
    for (int kk = 0; kk < 2; kk++) {
      const int sl = ((kk * 4 + kg) ^ rx) * 8;
#pragma unroll
      for (int i = 0; i < 4; i++)
        af[kk][i] = *reinterpret_cast<const bf16x8s*>(&Ab[(arow + i * 16) * 64 + sl]);
#pragma unroll
      for (int j = 0; j < NF; j++)
        bq[kk][j] = *reinterpret_cast<const bf16x8s*>(&Bb[(brow + j * 16) * 64 + sl]);
    }
    asm volatile("s_waitcnt lgkmcnt(0)" ::: "memory");  // frags in regs
    asm volatile("s_barrier" ::: "memory");             // all waves done reading

    if (t + 2 < nt) stage(cur, (t + 2) << 6);  // overwrite just-read buffer

#pragma unroll
    for (int kk = 0; kk < 2; kk++)
#pragma unroll
      for (int i = 0; i < 4; i++)
#pragma unroll
        for (int j = 0; j < NF; j++)
          acc[i][j] = __builtin_amdgcn_mfma_f32_16x16x32_bf16(
              af[kk][i], bq[kk][j], acc[i][j], 0, 0, 0);
  }

  // ---- epilogue: dump activated tile to LDS, then coalesced write-out ----
  __hip_bfloat16* Ct = smem;
#pragma unroll
  for (int i = 0; i < 4; i++)
#pragma unroll
    for (int j = 0; j < NF; j++) {
      int cl = wc * (BN / 2) + j * 16 + lr;      // col within tile
      float bv = bias[n0 + cl];
#pragma unroll
      for (int r = 0; r < 4; r++) {
        int rl = wr * 64 + i * 16 + kg * 4 + r;  // row within tile
        float v = acc[i][j][r] + bv;
        if (ACT == 1) v = 1.f / (1.f + __expf(-v));
        else if (ACT == 2) {
          float x = v;
          float z = 1.5957691216057308f * (x + 0.044715f * x * x * x);
          v = x / (1.f + __expf(-z));
        }
        if (RADD) v += __bfloat162float(R[(size_t)(m0 + rl) * N + n0 + cl]);
        Ct[rl * CP + cl] = __float2bfloat16(v);
      }
    }
  __syncthreads();

  // coalesced write-out: 16B chunks, 16 consecutive lanes = 256B runs
  constexpr int CPR = BN / 8;               // 16B chunks per row (12/16/24)
  constexpr int NPASS = 128 * CPR / 256;    // 6/8/12 passes
#pragma unroll
  for (int p = 0; p < NPASS; ++p) {
    int idx = p * 256 + tid;
    int row = idx / CPR;
    int ch  = idx - row * CPR;
    uint4 d = *reinterpret_cast<const uint4*>(&Ct[row * CP + ch * 8]);
    *reinterpret_cast<uint4*>(&Cb[(size_t)(m0 + row) * N + n0 + ch * 8]) = d;
  }
}

// ---------------------------------------------------------------------------
extern "C" void kernel_launch(void* const* d_in, const int* in_sizes, int n_in,
                              void* d_out, int out_size, void* d_ws, size_t ws_size,
                              hipStream_t stream)
{
  const int*   ids  = (const int*)d_in[0];
  const float* wemb = (const float*)d_in[1];
  const float* pemb = (const float*)d_in[2];
  const float* elns = (const float*)d_in[3];
  const float* elnb = (const float*)d_in[4];
  const float* retW = (const float*)d_in[5];
  const float* retb = (const float*)d_in[6];
  const float* ln1s = (const float*)d_in[7];
  const float* ln1b = (const float*)d_in[8];
  const float* W1   = (const float*)d_in[9];
  const float* b1   = (const float*)d_in[10];
  const float* W2   = (const float*)d_in[11];
  const float* b2   = (const float*)d_in[12];
  const float* ln2s = (const float*)d_in[13];
  const float* ln2b = (const float*)d_in[14];
  const float* fins = (const float*)d_in[15];
  const float* finb = (const float*)d_in[16];
  float* out = (float*)d_out;

  char* ws = (char*)d_ws;
  size_t off = 0;
  __hip_bfloat16* retWt = (__hip_bfloat16*)(ws + off); off += (size_t)NL * HD * HD * 2;
  __hip_bfloat16* W1t   = (__hip_bfloat16*)(ws + off); off += (size_t)NL * HD * ID * 2;
  __hip_bfloat16* W2t   = (__hip_bfloat16*)(ws + off); off += (size_t)NL * ID * HD * 2;
  __hip_bfloat16* hb    = (__hip_bfloat16*)(ws + off); off += (size_t)ROWS * HD * 2;  // residual h
  __hip_bfloat16* h1b   = (__hip_bfloat16*)(ws + off); off += (size_t)ROWS * HD * 2;  // h1
  __hip_bfloat16* yb    = (__hip_bfloat16*)(ws + off); off += (size_t)ROWS * HD * 2;  // h1+ffn2
  __hip_bfloat16* gb    = (__hip_bfloat16*)(ws + off); off += (size_t)ROWS * ID * 2;  // s / gelu out
  __hip_bfloat16* sb = gb;   // sigmoid out aliases gb (consumed before FFN1 rewrites)

  // all three weight transposes in one launch (20736 tiles)
  transpose_all_kernel<<<dim3(20736), dim3(32, 8), 0, stream>>>(
      retW, W1, W2, retWt, W1t, W2t);

  embed_ln_kernel<<<ROWS/4, 256, 0, stream>>>(ids, wemb, pemb, elns, elnb, hb);

  for (int l = 0; l < NL; l++) {
    // s = sigmoid(h @ retW + rb) -> sb (bf16). BN=96 (512 blocks = 2/CU)
    gemm_mfma_kernel<96, 1, 0><<<dim3(ROWS/128, HD/96), 256, 0, stream>>>(
        hb, retWt + (size_t)l * HD * HD, retb + (size_t)l * HD,
        nullptr, sb, ROWS, HD, HD);
    // h1 = LN(h + retention(s))  [fused scan+LN, warm-up 16]
    scan_ln_kernel<<<NB * (SL/32), 768, 0, stream>>>(sb, hb,
        ln1s + (size_t)l * HD, ln1b + (size_t)l * HD, h1b);
    // g = gelu(h1 @ W1 + b1) -> gb (bf16). BN=192 (1024 blocks = 4/CU)
    gemm_mfma_kernel<192, 2, 0><<<dim3(ROWS/128, ID/192), 256, 0, stream>>>(
        h1b, W1t + (size_t)l * ID * HD, b1 + (size_t)l * ID,
        nullptr, gb, ROWS, ID, HD);
    // y = h1 + (g @ W2 + b2) -> yb (bf16). BN=96 (512 blocks = 2/CU)
    gemm_mfma_kernel<96, 0, 1><<<dim3(ROWS/128, HD/96), 256, 0, stream>>>(
        gb, W2t + (size_t)l * HD * ID, b2 + (size_t)l * HD,
        h1b, yb, ROWS, HD, ID);
    if (l < NL - 1) {
      // h = LN(y)
      ln_row_kernel<0><<<ROWS/4, 256, 0, stream>>>(yb,
          ln2s + (size_t)l * HD, ln2b + (size_t)l * HD, hb, nullptr);
    } else {
      // last layer: out = LNf(bf16(LN2(y))) fused — skips hb round-trip
      ln2_final_kernel<<<ROWS/4, 256, 0, stream>>>(yb,
          ln2s + (size_t)l * HD, ln2b + (size_t)l * HD, fins, finb, out);
    }
  }
}